// Round 14
// baseline (1809.430 us; speedup 1.0000x reference)
//
#include <hip/hip_runtime.h>

#define B_   16
#define C_   1024
#define Q_   128
#define S_   1152
#define D_   512
#define H_   8
#define HID_ 2048
#define L_   6
#define M_   (B_*S_)   // 18432 tokens
#define MQ_  (B_*Q_)   // 2048 query tokens
#define QSC_ 0.18033688011f   // 0.125 * log2(e): folds 1/sqrt(64) and 1/ln2 into Q

typedef short bf16x8 __attribute__((ext_vector_type(8)));
typedef float f32x4  __attribute__((ext_vector_type(4)));
#define MFMA16(a,b,c) __builtin_amdgcn_mfma_f32_16x16x32_bf16(a,b,c,0,0,0)

__device__ __forceinline__ unsigned short f2b(float f){
  union { float f; unsigned u; } v; v.f = f;
  return (unsigned short)((v.u + 0x7FFF + ((v.u >> 16) & 1)) >> 16);  // RNE
}
__device__ __forceinline__ float b2f(unsigned short u){
  return __uint_as_float((unsigned)u << 16);
}
__device__ __forceinline__ void gload16(const void* g, void* l){
  __builtin_amdgcn_global_load_lds((const __attribute__((address_space(1))) void*)g,
                                   (__attribute__((address_space(3))) void*)l, 16, 0, 0);
}
__device__ __forceinline__ float waveSum(float v){
  #pragma unroll
  for (int o = 32; o > 0; o >>= 1) v += __shfl_down(v, o, 64);
  return v;
}

// ---------------- fp32 -> bf16 weight conversion ----------------------------------
__global__ __launch_bounds__(256) void f2b_kernel(
    const float* __restrict__ in, unsigned short* __restrict__ out, int n4)
{
  int i = blockIdx.x*256 + threadIdx.x;
  for (; i < n4; i += gridDim.x*256) {
    float4 v = ((const float4*)in)[i];
    ushort4 o = { f2b(v.x), f2b(v.y), f2b(v.z), f2b(v.w) };
    ((ushort4*)out)[i] = o;
  }
}

// ---------------- in_proj_w -> bf16 with Q-rows pre-scaled by QSC_ -----------------
__global__ __launch_bounds__(256) void f2bq_kernel(
    const float* __restrict__ in, unsigned short* __restrict__ out, int n4)
{
  int i = blockIdx.x*256 + threadIdx.x;
  for (; i < n4; i += gridDim.x*256) {
    const int row = (i >> 7) % 1536;          // 128 float4 per 512-col row
    const float s = (row < 512) ? QSC_ : 1.f;
    float4 v = ((const float4*)in)[i];
    ushort4 o = { f2b(v.x*s), f2b(v.y*s), f2b(v.z*s), f2b(v.w*s) };
    ((ushort4*)out)[i] = o;
  }
}

// ---------------- in_proj_b scaled copy (Q part * QSC_) ----------------------------
__global__ __launch_bounds__(256) void sbias_kernel(
    const float* __restrict__ in, float* __restrict__ out)
{
  int idx = blockIdx.x*256 + threadIdx.x;     // L_*1536 = 9216
  if (idx < L_*1536) {
    int j = idx % 1536;
    out[idx] = in[idx] * (j < 512 ? QSC_ : 1.f);
  }
}

// ---------------- pack XY [M,128] bf16: x | y/0 | 1 | isq | zeros ------------------
__global__ __launch_bounds__(256) void packxy_kernel(
    const float* __restrict__ x_c, const float* __restrict__ y_c,
    const float* __restrict__ x_q, unsigned short* __restrict__ XY)
{
  int idx = blockIdx.x*256 + threadIdx.x;
  const int n = M_*128;
  for (; idx < n; idx += gridDim.x*256) {
    int row = idx >> 7, col = idx & 127;
    int bb = row / S_, s = row % S_;
    float v;
    if (col < 64) {
      v = (s < C_) ? x_c[((size_t)bb*C_ + s)*64 + col]
                   : x_q[((size_t)bb*Q_ + (s - C_))*64 + col];
    } else if (col < 96) {
      v = (s < C_) ? y_c[((size_t)bb*C_ + s)*32 + (col - 64)] : 0.f;
    } else if (col == 96) {
      v = 1.f;
    } else if (col == 97) {
      v = (s >= C_) ? 1.f : 0.f;
    } else v = 0.f;
    XY[idx] = f2b(v);
  }
}

// ---------------- build Wemb [512][128] bf16 (W_val^T | b_val | q_emb | 0) ---------
__global__ __launch_bounds__(256) void wemb_kernel(
    const float* __restrict__ W_val, const float* __restrict__ b_val,
    const float* __restrict__ q_emb, unsigned short* __restrict__ Wemb)
{
  int idx = blockIdx.x*256 + threadIdx.x;   // 512*128 = 65536 = 256*256
  int nn = idx >> 7, k = idx & 127;
  float v;
  if (k < 96)       v = W_val[k*D_ + nn];
  else if (k == 96) v = b_val[nn];
  else if (k == 97) v = q_emb[nn];
  else              v = 0.f;
  Wemb[idx] = f2b(v);
}

// ---------------- gather query rows (bf16) -> compact [MQ_,512] --------------------
__global__ __launch_bounds__(256) void gatherq_kernel(
    const unsigned short* __restrict__ X, unsigned short* __restrict__ Xq)
{
  int row = blockIdx.x;                 // 0..MQ_-1
  int bb = row >> 7, qi = row & 127;
  const unsigned short* src = X + ((size_t)bb*S_ + C_ + qi)*D_;
  unsigned short* dst = Xq + (size_t)row*D_;
  int tid = threadIdx.x;
  dst[tid] = src[tid];
  dst[tid + 256] = src[tid + 256];
}

// T2 swizzle: LDS slot (row, c) holds global chunk c ^ sw(row); linear gload_lds
// dest + pre-swizzled SOURCE + swizzled READ. sw period 8 in row (64 ≡ 0 mod 8,
// so the +64-row staging call shares the per-lane offset).
#define SWZ(row) (((row) >> 1) & 3)

// ---------------- bf16 MFMA GEMM, 2-phase double-buffered, 128x128 tile ------------
// BOUT: 0 = f32 out, 1 = bf16 out.
template<int RELU, int BOUT>
__global__ __launch_bounds__(256) void bgemm_kernel(
    const unsigned short* __restrict__ A, const unsigned short* __restrict__ W,
    const float* __restrict__ bias,
    float* __restrict__ Cf, unsigned short* __restrict__ Cb, int Nn, int Kk)
{
  __shared__ short As[2][4096];     // [buf][128][32] bf16
  __shared__ short Bs[2][4096];
  int lin = blockIdx.y * gridDim.x + blockIdx.x;
  const int nwg = gridDim.x * gridDim.y;
  const int cpx = nwg >> 3;
  lin = (lin & 7) * cpx + (lin >> 3);
  const int bm = (lin / gridDim.x) * 128, bn = (lin % gridDim.x) * 128;

  const int tid = threadIdx.x;
  const int w = tid >> 6, lane = tid & 63, l15 = lane & 15, l4 = lane >> 4;
  const int wm = w >> 1, wn = w & 1;
  f32x4 acc[4][4] = {};
  const size_t strA = (size_t)Kk * 2;          // bytes per row
  const char* Abase = (const char*)A + (size_t)bm * strA;
  const char* Wbase = (const char*)W + (size_t)bn * strA;
  const int srow = tid >> 2;
  const int schunk = (tid & 3) ^ SWZ(srow);    // pre-swizzled source chunk
  const size_t soff = (size_t)srow * strA + (size_t)(schunk * 16);
  const int ldsOff = w * 1024;

#define STAGEK(K0, BUF) do { \
    const char* a0_ = Abase + soff + (size_t)(K0)*2; \
    const char* b0_ = Wbase + soff + (size_t)(K0)*2; \
    char* la_ = (char*)As + (BUF)*8192 + ldsOff; \
    char* lb_ = (char*)Bs + (BUF)*8192 + ldsOff; \
    gload16(a0_,            la_); \
    gload16(a0_ + 64*strA,  la_ + 4096); \
    gload16(b0_,            lb_); \
    gload16(b0_ + 64*strA,  lb_ + 4096); \
  } while(0)

  STAGEK(0, 0);
  const int nk = Kk >> 5;
  for (int t = 0; t < nk; t++) {
    __syncthreads();                       // buf[t&1] staged; prior reads done
    if (t + 1 < nk) STAGEK((t+1)*32, (t+1)&1);   // prefetch under this tile's MFMAs
    const short* AsC = (const short*)As + (t&1)*4096;
    const short* BsC = (const short*)Bs + (t&1)*4096;
    bf16x8 af[4], bfr[4];
    #pragma unroll
    for (int mf = 0; mf < 4; mf++) {
      const int ar = wm*64 + mf*16 + l15;
      af[mf] = *(const bf16x8*)(AsC + ar*32 + (l4 ^ SWZ(ar))*8);
    }
    #pragma unroll
    for (int nf = 0; nf < 4; nf++) {
      const int br = wn*64 + nf*16 + l15;
      bfr[nf] = *(const bf16x8*)(BsC + br*32 + (l4 ^ SWZ(br))*8);
    }
    #pragma unroll
    for (int mf = 0; mf < 4; mf++)
      #pragma unroll
      for (int nf = 0; nf < 4; nf++)
        acc[mf][nf] = MFMA16(af[mf], bfr[nf], acc[mf][nf]);
  }
#undef STAGEK

  #pragma unroll
  for (int mf = 0; mf < 4; mf++) {
    #pragma unroll
    for (int nf = 0; nf < 4; nf++) {
      const int ccol = bn + wn*64 + nf*16 + l15;
      const float bv = bias[ccol];
      #pragma unroll
      for (int r = 0; r < 4; r++) {
        const int rrow = bm + wm*64 + mf*16 + l4*4 + r;
        float o = acc[mf][nf][r] + bv;
        if (RELU) o = fmaxf(o, 0.f);
        if (BOUT == 1) Cb[(size_t)rrow*Nn + ccol] = f2b(o);
        else           Cf[(size_t)rrow*Nn + ccol] = o;
      }
    }
  }
}

// ---------------- split-K=2 GEMM (FFN2): 128x128 tile, fp32 partials ---------------
// grid (4, 288): after swizzle, rowblk 0..287 -> z = rowblk/144, bm = (rowblk%144)*128.
// slice 0 adds bias + bf16 residual -> C0; slice 1 raw partial -> C1.
__global__ __launch_bounds__(256) void bgemm_sk_kernel(
    const unsigned short* __restrict__ A, const unsigned short* __restrict__ W,
    const float* __restrict__ bias, const unsigned short* __restrict__ Rsd,
    float* __restrict__ C0, float* __restrict__ C1, int Nn, int Kfull)
{
  __shared__ short As[2][4096];
  __shared__ short Bs[2][4096];
  int lin = blockIdx.y * gridDim.x + blockIdx.x;
  const int nwg = gridDim.x * gridDim.y;        // 1152
  const int cpx = nwg >> 3;
  lin = (lin & 7) * cpx + (lin >> 3);
  int rowblk = lin / gridDim.x;
  const int bn = (lin % gridDim.x) * 128;
  const int z = (rowblk >= 144) ? 1 : 0;
  if (z) rowblk -= 144;
  const int bm = rowblk * 128;
  const int KS = Kfull >> 1;                    // 1024 per slice

  const int tid = threadIdx.x;
  const int w = tid >> 6, lane = tid & 63, l15 = lane & 15, l4 = lane >> 4;
  const int wm = w >> 1, wn = w & 1;
  f32x4 acc[4][4] = {};
  const size_t strA = (size_t)Kfull * 2;        // full row stride (bytes)
  const char* Abase = (const char*)A + (size_t)bm * strA + (size_t)z*KS*2;
  const char* Wbase = (const char*)W + (size_t)bn * strA + (size_t)z*KS*2;
  const int srow = tid >> 2;
  const int schunk = (tid & 3) ^ SWZ(srow);
  const size_t soff = (size_t)srow * strA + (size_t)(schunk * 16);
  const int ldsOff = w * 1024;

#define STAGEK(K0, BUF) do { \
    const char* a0_ = Abase + soff + (size_t)(K0)*2; \
    const char* b0_ = Wbase + soff + (size_t)(K0)*2; \
    char* la_ = (char*)As + (BUF)*8192 + ldsOff; \
    char* lb_ = (char*)Bs + (BUF)*8192 + ldsOff; \
    gload16(a0_,            la_); \
    gload16(a0_ + 64*strA,  la_ + 4096); \
    gload16(b0_,            lb_); \
    gload16(b0_ + 64*strA,  lb_ + 4096); \
  } while(0)

  STAGEK(0, 0);
  const int nk = KS >> 5;                       // 32
  for (int t = 0; t < nk; t++) {
    __syncthreads();
    if (t + 1 < nk) STAGEK((t+1)*32, (t+1)&1);
    const short* AsC = (const short*)As + (t&1)*4096;
    const short* BsC = (const short*)Bs + (t&1)*4096;
    bf16x8 af[4], bfr[4];
    #pragma unroll
    for (int mf = 0; mf < 4; mf++) {
      const int ar = wm*64 + mf*16 + l15;
      af[mf] = *(const bf16x8*)(AsC + ar*32 + (l4 ^ SWZ(ar))*8);
    }
    #pragma unroll
    for (int nf = 0; nf < 4; nf++) {
      const int br = wn*64 + nf*16 + l15;
      bfr[nf] = *(const bf16x8*)(BsC + br*32 + (l4 ^ SWZ(br))*8);
    }
    #pragma unroll
    for (int mf = 0; mf < 4; mf++)
      #pragma unroll
      for (int nf = 0; nf < 4; nf++)
        acc[mf][nf] = MFMA16(af[mf], bfr[nf], acc[mf][nf]);
  }
#undef STAGEK

  #pragma unroll
  for (int mf = 0; mf < 4; mf++) {
    #pragma unroll
    for (int nf = 0; nf < 4; nf++) {
      const int ccol = bn + wn*64 + nf*16 + l15;
      #pragma unroll
      for (int r = 0; r < 4; r++) {
        const int rrow = bm + wm*64 + mf*16 + l4*4 + r;
        if (z == 0) {
          C0[(size_t)rrow*Nn + ccol] = acc[mf][nf][r] + bias[ccol]
                                     + b2f(Rsd[(size_t)rrow*Nn + ccol]);
        } else {
          C1[(size_t)rrow*Nn + ccol] = acc[mf][nf][r];
        }
      }
    }
  }
}

// ---------------- bf16 MFMA GEMM, 128x64 tile, 3-buffer counted-vmcnt + T2 swizzle -
// bf16 residual, f32 out. (out-proj / compact layer-6 path)
__global__ __launch_bounds__(256) void bgemm64_kernel(
    const unsigned short* __restrict__ A, const unsigned short* __restrict__ W,
    const float* __restrict__ bias, const unsigned short* __restrict__ Rsd,
    float* __restrict__ Cf, int Nn, int Kk)
{
  __shared__ short As[3][4096];     // [buf][128][32] bf16
  __shared__ short Bs[3][2048];     // [buf][64][32]  bf16
  int lin = blockIdx.y * gridDim.x + blockIdx.x;
  const int nwg = gridDim.x * gridDim.y;
  const int cpx = nwg >> 3;
  lin = (lin & 7) * cpx + (lin >> 3);
  const int bm = (lin / gridDim.x) * 128, bn = (lin % gridDim.x) * 64;

  const int tid = threadIdx.x;
  const int w = tid >> 6, lane = tid & 63, l15 = lane & 15, l4 = lane >> 4;
  f32x4 acc[2][4] = {};
  const size_t strA = (size_t)Kk * 2;
  const char* Abase = (const char*)A + (size_t)bm * strA;
  const char* Wbase = (const char*)W + (size_t)bn * strA;
  const int srow = tid >> 2;
  const int schunk = (tid & 3) ^ SWZ(srow);
  const size_t soff = (size_t)srow * strA + (size_t)(schunk * 16);
  const int ldsOff = w * 1024;

#define STAGEK64(K0, BUF) do { \
    const char* a0_ = Abase + soff + (size_t)(K0)*2; \
    const char* b0_ = Wbase + soff + (size_t)(K0)*2; \
    char* la_ = (char*)As + (BUF)*8192 + ldsOff; \
    char* lb_ = (char*)Bs + (BUF)*4096 + ldsOff; \
    gload16(a0_,            la_); \
    gload16(a0_ + 64*strA,  la_ + 4096); \
    gload16(b0_,            lb_); \
  } while(0)

  const int nk = Kk >> 5;
  STAGEK64(0, 0);
  STAGEK64(32, 1);
  int rb = 0;
  for (int t = 0; t < nk; t++) {
    if (t + 1 < nk) asm volatile("s_waitcnt vmcnt(3)" ::: "memory");
    else            asm volatile("s_waitcnt vmcnt(0)" ::: "memory");
    __builtin_amdgcn_s_barrier();
    __builtin_amdgcn_sched_barrier(0);
    if (t + 2 < nk) {
      int wbuf = rb + 2; if (wbuf >= 3) wbuf -= 3;
      STAGEK64((t+2)*32, wbuf);
    }
    const short* AsC = (const short*)As + rb*4096;
    const short* BsC = (const short*)Bs + rb*2048;
    bf16x8 af[2], bfr[4];
    #pragma unroll
    for (int mf = 0; mf < 2; mf++) {
      const int ar = w*32 + mf*16 + l15;
      af[mf] = *(const bf16x8*)(AsC + ar*32 + (l4 ^ SWZ(ar))*8);
    }
    #pragma unroll
    for (int nf = 0; nf < 4; nf++) {
      const int br = nf*16 + l15;
      bfr[nf] = *(const bf16x8*)(BsC + br*32 + (l4 ^ SWZ(br))*8);
    }
    #pragma unroll
    for (int mf = 0; mf < 2; mf++)
      #pragma unroll
      for (int nf = 0; nf < 4; nf++)
        acc[mf][nf] = MFMA16(af[mf], bfr[nf], acc[mf][nf]);
    rb++; if (rb >= 3) rb = 0;
  }
#undef STAGEK64

  #pragma unroll
  for (int mf = 0; mf < 2; mf++) {
    #pragma unroll
    for (int nf = 0; nf < 4; nf++) {
      const int ccol = bn + nf*16 + l15;
      const float bv = bias[ccol];
      #pragma unroll
      for (int r = 0; r < 4; r++) {
        const int rrow = bm + w*32 + mf*16 + l4*4 + r;
        float o = acc[mf][nf][r] + bv + b2f(Rsd[(size_t)rrow*Nn + ccol]);
        Cf[(size_t)rrow*Nn + ccol] = o;
      }
    }
  }
}

// ---------------- MFMA flash attention, QBLK=64, base-2 softmax, XCD swizzle -------
__global__ __launch_bounds__(256) void mattn_kernel(
    const unsigned short* __restrict__ QKV, unsigned short* __restrict__ Ctx,
    int nqt, int qoff, int orows)
{
  __shared__ short Ks[64*72];      // [key][hd], 144B row stride
  __shared__ short Vt[64*72];      // [hd][key] transposed, slot-XOR swizzled
  __shared__ short Ps[4*16*72];    // per-wave P tile [q][key]
  int bid = blockIdx.x;
  const int nwg = gridDim.x;                 // always % 8 == 0 (2304 or 256)
  bid = (bid & 7) * (nwg >> 3) + (bid >> 3);
  const int qt = bid % nqt;
  const int h  = (bid / nqt) % H_;
  const int bb = bid / (nqt*H_);
  const int tid = threadIdx.x;
  const int w = tid >> 6, lane = tid & 63, l15 = lane & 15, l4 = lane >> 4;

  const size_t rowQ = (size_t)bb*S_ + qoff + (size_t)qt*64 + w*16 + l15;
  const unsigned short* qp = QKV + rowQ*1536 + h*64;
  const bf16x8 qf0 = *(const bf16x8*)(qp + l4*8);
  const bf16x8 qf1 = *(const bf16x8*)(qp + 32 + l4*8);

  const unsigned short* Kg = QKV + (size_t)bb*S_*1536 + 512 + h*64;
  const unsigned short* Vg = Kg + 512;

  f32x4 ctx[4] = {};
  f32x4 lacc = {};
  float m_r[4];
  #pragma unroll
  for (int r = 0; r < 4; r++) m_r[r] = -3.0e38f;

  const bf16x8 onesv = {(short)0x3F80,(short)0x3F80,(short)0x3F80,(short)0x3F80,
                        (short)0x3F80,(short)0x3F80,(short)0x3F80,(short)0x3F80};

  char* PsW = (char*)Ps + w*2304;

  const int skey = tid >> 3, shc = tid & 7;
  const int vp   = tid >> 3, vhc = tid & 7;

  const unsigned short* gK = Kg + (size_t)skey*1536 + shc*8;
  const unsigned short* gV = Vg + (size_t)(2*vp)*1536 + vhc*8;
  bf16x8 k0v = *(const bf16x8*)gK;
  bf16x8 k1v = *(const bf16x8*)(gK + 32*1536);
  bf16x8 c0  = *(const bf16x8*)gV;
  bf16x8 c1  = *(const bf16x8*)(gV + 1536);

  for (int kt = 0; kt < 16; kt++) {
    __syncthreads();
    *(bf16x8*)((char*)Ks + skey*144      + shc*16) = k0v;
    *(bf16x8*)((char*)Ks + (skey+32)*144 + shc*16) = k1v;
    #pragma unroll
    for (int j = 0; j < 8; j++) {
      const int hd = vhc*8 + j;
      unsigned int val = (unsigned int)(unsigned short)c0[j]
                       | ((unsigned int)(unsigned short)c1[j] << 16);
      *(unsigned int*)((char*)Vt + hd*144 + ((4*vp) ^ (vhc<<4))) = val;
    }
    __syncthreads();
    if (kt < 15) {
      const unsigned short* nK = gK + (size_t)(kt+1)*98304;
      const unsigned short* nV = gV + (size_t)(kt+1)*98304;
      k0v = *(const bf16x8*)nK;
      k1v = *(const bf16x8*)(nK + 32*1536);
      c0  = *(const bf16x8*)nV;
      c1  = *(const bf16x8*)(nV + 1536);
    }

    f32x4 sac[4] = {};
    __builtin_amdgcn_s_setprio(1);
    #pragma unroll
    for (int nf = 0; nf < 4; nf++) {
      const char* kb = (char*)Ks + (nf*16 + l15)*144 + l4*16;
      bf16x8 b0 = *(const bf16x8*)kb;
      bf16x8 b1 = *(const bf16x8*)(kb + 64);
      sac[nf] = MFMA16(qf0, b0, sac[nf]);
      sac[nf] = MFMA16(qf1, b1, sac[nf]);
    }
    __builtin_amdgcn_s_setprio(0);

    float lmax[4];
    #pragma unroll
    for (int r = 0; r < 4; r++)
      lmax[r] = fmaxf(fmaxf(sac[0][r], sac[1][r]), fmaxf(sac[2][r], sac[3][r]));
    int ok = 1;
    #pragma unroll
    for (int r = 0; r < 4; r++) ok &= (lmax[r] <= m_r[r] + 11.5409f) ? 1 : 0;
    if (!__all(ok)) {
      #pragma unroll
      for (int r = 0; r < 4; r++) {
        float t = lmax[r];
        t = fmaxf(t, __shfl_xor(t, 1, 64));
        t = fmaxf(t, __shfl_xor(t, 2, 64));
        t = fmaxf(t, __shfl_xor(t, 4, 64));
        t = fmaxf(t, __shfl_xor(t, 8, 64));
        const float mn = fmaxf(m_r[r], t);
        const float scl = __builtin_amdgcn_exp2f(m_r[r] - mn);
        m_r[r] = mn;
        lacc[r] *= scl;
        ctx[0][r] *= scl; ctx[1][r] *= scl;
        ctx[2][r] *= scl; ctx[3][r] *= scl;
      }
    }
    #pragma unroll
    for (int r = 0; r < 4; r++) {
      unsigned short* pw = (unsigned short*)(PsW + (l4*4 + r)*144);
      const float m0 = m_r[r];
      pw[ 0 + l15] = (unsigned short)(__float_as_uint(__builtin_amdgcn_exp2f(sac[0][r] - m0)) >> 16);
      pw[16 + l15] = (unsigned short)(__float_as_uint(__builtin_amdgcn_exp2f(sac[1][r] - m0)) >> 16);
      pw[32 + l15] = (unsigned short)(__float_as_uint(__builtin_amdgcn_exp2f(sac[2][r] - m0)) >> 16);
      pw[48 + l15] = (unsigned short)(__float_as_uint(__builtin_amdgcn_exp2f(sac[3][r] - m0)) >> 16);
    }

    const char* pb = PsW + l15*144 + l4*16;
    const bf16x8 pf0 = *(const bf16x8*)pb;
    const bf16x8 pf1 = *(const bf16x8*)(pb + 64);
    __builtin_amdgcn_s_setprio(1);
    lacc = MFMA16(pf0, onesv, lacc);
    lacc = MFMA16(pf1, onesv, lacc);
    #pragma unroll
    for (int hf = 0; hf < 4; hf++) {
      const int hd = hf*16 + l15;
      const int hc = (hd >> 3) & 7;
      const char* vb = (char*)Vt + hd*144;
      bf16x8 v0 = *(const bf16x8*)(vb + ((l4*16)     ^ (hc<<4)));
      bf16x8 v1 = *(const bf16x8*)(vb + (((l4+4)*16) ^ (hc<<4)));
      ctx[hf] = MFMA16(pf0, v0, ctx[hf]);
      ctx[hf] = MFMA16(pf1, v1, ctx[hf]);
    }
    __builtin_amdgcn_s_setprio(0);
  }

  #pragma unroll
  for (int r = 0; r < 4; r++) {
    const float invl = 1.0f / lacc[r];
    const size_t row = (size_t)bb*orows + (size_t)qt*64 + w*16 + l4*4 + r;
    unsigned short* op = Ctx + row*512 + h*64;
    op[ 0 + l15] = f2b(ctx[0][r]*invl);
    op[16 + l15] = f2b(ctx[1][r]*invl);
    op[32 + l15] = f2b(ctx[2][r]*invl);
    op[48 + l15] = f2b(ctx[3][r]*invl);
  }
}

// ---------------- row LayerNorm over D=512: fp32 in, bf16 out ----------------------
__global__ __launch_bounds__(256) void ln_kernel(
    const float* __restrict__ Yin, const float* __restrict__ g, const float* __restrict__ b,
    unsigned short* __restrict__ Xb)
{
  int row = blockIdx.x, tid = threadIdx.x;
  const float* yr = Yin + (size_t)row*D_;
  float v0 = yr[tid], v1 = yr[tid + 256];
  __shared__ float red[4];
  float s = waveSum(v0 + v1);
  if ((tid & 63) == 0) red[tid >> 6] = s;
  __syncthreads();
  float mu = (red[0] + red[1] + red[2] + red[3]) * (1.f/512.f);
  __syncthreads();
  float d0 = v0 - mu, d1 = v1 - mu;
  float ss = waveSum(d0*d0 + d1*d1);
  if ((tid & 63) == 0) red[tid >> 6] = ss;
  __syncthreads();
  float inv = rsqrtf((red[0] + red[1] + red[2] + red[3]) * (1.f/512.f) + 1e-5f);
  Xb[(size_t)row*D_ + tid]       = f2b(d0 * inv * g[tid]       + b[tid]);
  Xb[(size_t)row*D_ + tid + 256] = f2b(d1 * inv * g[tid + 256] + b[tid + 256]);
}

// ---------------- LN over sum of two fp32 partials (split-K FFN2) ------------------
__global__ __launch_bounds__(256) void lnsum_kernel(
    const float* __restrict__ Y0, const float* __restrict__ Y1,
    const float* __restrict__ g, const float* __restrict__ b,
    unsigned short* __restrict__ Xb)
{
  int row = blockIdx.x, tid = threadIdx.x;
  const float* y0 = Y0 + (size_t)row*D_;
  const float* y1 = Y1 + (size_t)row*D_;
  float v0 = y0[tid] + y1[tid];
  float v1 = y0[tid + 256] + y1[tid + 256];
  __shared__ float red[4];
  float s = waveSum(v0 + v1);
  if ((tid & 63) == 0) red[tid >> 6] = s;
  __syncthreads();
  float mu = (red[0] + red[1] + red[2] + red[3]) * (1.f/512.f);
  __syncthreads();
  float d0 = v0 - mu, d1 = v1 - mu;
  float ss = waveSum(d0*d0 + d1*d1);
  if ((tid & 63) == 0) red[tid >> 6] = ss;
  __syncthreads();
  float inv = rsqrtf((red[0] + red[1] + red[2] + red[3]) * (1.f/512.f) + 1e-5f);
  Xb[(size_t)row*D_ + tid]       = f2b(d0 * inv * g[tid]       + b[tid]);
  Xb[(size_t)row*D_ + tid + 256] = f2b(d1 * inv * g[tid + 256] + b[tid + 256]);
}

// ---------------- head: Xq[row](bf16) @ W_head[512,32] + b_head --------------------
__global__ __launch_bounds__(64) void head_kernel(
    const unsigned short* __restrict__ Xq, const float* __restrict__ W_head,
    const float* __restrict__ b_head, float* __restrict__ out)
{
  int row = blockIdx.x;            // 0..MQ_-1
  const unsigned short* xr = Xq + (size_t)row*D_;
  __shared__ float xs[512];
  int tid = threadIdx.x;
  for (int i = tid; i < 512; i += 64) xs[i] = b2f(xr[i]);
  __syncthreads();
  if (tid < 32) {
    float acc = b_head[tid];
    #pragma unroll 8
    for (int k = 0; k < 512; k++) acc += xs[k] * W_head[k*32 + tid];
    out[(size_t)row*32 + tid] = acc;
  }
}

extern "C" void kernel_launch(void* const* d_in, const int* in_sizes, int n_in,
                              void* d_out, int out_size, void* d_ws, size_t ws_size,
                              hipStream_t stream)
{
  const float* x_c      = (const float*)d_in[0];
  const float* y_c      = (const float*)d_in[1];
  const float* x_q      = (const float*)d_in[2];
  const float* W_val    = (const float*)d_in[3];
  const float* b_val    = (const float*)d_in[4];
  const float* q_emb    = (const float*)d_in[5];
  const float* in_proj_w= (const float*)d_in[6];
  const float* in_proj_b= (const float*)d_in[7];
  const float* out_w    = (const float*)d_in[8];
  const float* out_b    = (const float*)d_in[9];
  const float* ln1_g    = (const float*)d_in[10];
  const float* ln1_b    = (const float*)d_in[11];
  const float* lin1_w   = (const float*)d_in[12];
  const float* lin1_b   = (const float*)d_in[13];
  const float* lin2_w   = (const float*)d_in[14];
  const float* lin2_b   = (const float*)d_in[15];
  const float* ln2_g    = (const float*)d_in[16];
  const float* ln2_b    = (const float*)d_in[17];
  const float* W_head   = (const float*)d_in[18];
  const float* b_head   = (const float*)d_in[19];
  float* out = (float*)d_out;

  // workspace layout (~250 MB); residual stream is bf16 (Xb1/Xb2), Yf = pre-LN fp32
  char* p = (char*)d_ws;
  float* Yf = (float*)p;                     p += (size_t)M_*D_*4;    // GEMM+res out
  unsigned short* hid  = (unsigned short*)p; p += (size_t)M_*HID_*2;
  unsigned short* Xb2  = (unsigned short*)p; p += (size_t)M_*D_*2;    // ln2/embed out
  unsigned short* qkv  = (unsigned short*)p; p += (size_t)M_*3*D_*2;
  unsigned short* Xb1  = qkv;                                          // alias: ln1 out (disjoint live range)
  float* Yf1 = (float*)(qkv + (size_t)M_*D_); // alias: split-K partial (upper 2/3 of qkv;
                                              // live FFN2->lnsum, disjoint from Xb1 & qkv uses)
  unsigned short* ctxb = (unsigned short*)p; p += (size_t)M_*D_*2;
  unsigned short* ipwB = (unsigned short*)p; p += (size_t)L_*3*D_*D_*2;
  unsigned short* owB  = (unsigned short*)p; p += (size_t)L_*D_*D_*2;
  unsigned short* w1B  = (unsigned short*)p; p += (size_t)L_*HID_*D_*2;
  unsigned short* w2B  = (unsigned short*)p; p += (size_t)L_*D_*HID_*2;
  unsigned short* XYb  = (unsigned short*)p; p += (size_t)M_*128*2;
  unsigned short* Wemb = (unsigned short*)p; p += (size_t)D_*128*2;
  float* zbias         = (float*)p;          p += 2048*4;
  float* qkvbias       = (float*)p;          p += L_*1536*4;

  // compact layer-6 buffers (alias XYb region, idle post-embed)
  unsigned short* ctxq  = ctxb;                                   // [MQ_,512]
  float*          Yfq   = Yf;                                     // [MQ_,512] fp32
  unsigned short* hidq  = hid;                                    // [MQ_,2048]
  unsigned short* Xqb2  = XYb;                                    // gathered residual
  unsigned short* Xqb1  = XYb + (size_t)MQ_*D_;                   // ln1 out

  (void)hipMemsetAsync(zbias, 0, 2048*4, stream);

  // convert weights to bf16 (Q rows of in_proj pre-scaled by 0.125*log2e)
  f2bq_kernel<<<512, 256, 0, stream>>>(in_proj_w, ipwB, L_*3*D_*D_/4);
  sbias_kernel<<<36, 256, 0, stream>>>(in_proj_b, qkvbias);
  f2b_kernel<<<512, 256, 0, stream>>>(out_w,     owB,  L_*D_*D_/4);
  f2b_kernel<<<512, 256, 0, stream>>>(lin1_w,    w1B,  L_*HID_*D_/4);
  f2b_kernel<<<512, 256, 0, stream>>>(lin2_w,    w2B,  L_*D_*HID_/4);
  wemb_kernel<<<256, 256, 0, stream>>>(W_val, b_val, q_emb, Wemb);
  packxy_kernel<<<1024, 256, 0, stream>>>(x_c, y_c, x_q, XYb);

  // embedding as GEMM (bf16 out -> Xb2)
  bgemm_kernel<0,1><<<dim3(4, 144), 256, 0, stream>>>(
      XYb, Wemb, zbias, nullptr, Xb2, D_, 128);

  for (int l = 0; l < L_ - 1; l++) {
    // QKV projection (bf16 out, scaled Q)
    bgemm_kernel<0,1><<<dim3(12, 144), 256, 0, stream>>>(
        Xb2, ipwB + (size_t)l*3*D_*D_, qkvbias + (size_t)l*3*D_,
        nullptr, qkv, 3*D_, D_);
    // attention (full: 18 q-tiles per (b,h))
    mattn_kernel<<<B_*H_*18, 256, 0, stream>>>(qkv, ctxb, 18, 0, S_);
    // out-proj + bf16 residual(Xb2) -> Yf fp32
    bgemm64_kernel<<<dim3(8, 144), 256, 0, stream>>>(
        ctxb, owB + (size_t)l*D_*D_, out_b + (size_t)l*D_, Xb2, Yf, D_, D_);
    ln_kernel<<<M_, 256, 0, stream>>>(Yf, ln1_g + (size_t)l*D_, ln1_b + (size_t)l*D_, Xb1);
    // FFN1 (relu, bf16 out)
    bgemm_kernel<1,1><<<dim3(16, 144), 256, 0, stream>>>(
        Xb1, w1B + (size_t)l*HID_*D_, lin1_b + (size_t)l*HID_,
        nullptr, hid, HID_, D_);
    // FFN2 split-K=2: slice0 -> Yf (+bias+res(Xb1)), slice1 -> Yf1 (raw)
    bgemm_sk_kernel<<<dim3(4, 288), 256, 0, stream>>>(
        hid, w2B + (size_t)l*D_*HID_, lin2_b + (size_t)l*D_, Xb1, Yf, Yf1, D_, HID_);
    lnsum_kernel<<<M_, 256, 0, stream>>>(Yf, Yf1, ln2_g + (size_t)l*D_, ln2_b + (size_t)l*D_, Xb2);
  }

  // ---------- layer 6 (l = L_-1): only query rows reach the head ----------
  {
    const int l = L_ - 1;
    bgemm_kernel<0,1><<<dim3(12, 144), 256, 0, stream>>>(
        Xb2, ipwB + (size_t)l*3*D_*D_, qkvbias + (size_t)l*3*D_,
        nullptr, qkv, 3*D_, D_);
    // attention only for the 2 query q-tiles per (b,h); compact output [MQ_,512]
    mattn_kernel<<<B_*H_*2, 256, 0, stream>>>(qkv, ctxq, 2, C_, Q_);
    // gather query rows of Xb2 -> Xqb2 (bf16)
    gatherq_kernel<<<MQ_, 256, 0, stream>>>(Xb2, Xqb2);
    // out-proj + residual(Xqb2) -> Yfq (M = 2048)
    bgemm64_kernel<<<dim3(8, 16), 256, 0, stream>>>(
        ctxq, owB + (size_t)l*D_*D_, out_b + (size_t)l*D_, Xqb2, Yfq, D_, D_);
    ln_kernel<<<MQ_, 256, 0, stream>>>(Yfq, ln1_g + (size_t)l*D_, ln1_b + (size_t)l*D_, Xqb1);
    // FFN1 (relu) compact
    bgemm_kernel<1,1><<<dim3(16, 16), 256, 0, stream>>>(
        Xqb1, w1B + (size_t)l*HID_*D_, lin1_b + (size_t)l*HID_,
        nullptr, hidq, HID_, D_);
    // FFN2 + residual(Xqb1) -> Yfq
    bgemm64_kernel<<<dim3(8, 16), 256, 0, stream>>>(
        hidq, w2B + (size_t)l*D_*HID_, lin2_b + (size_t)l*D_, Xqb1, Yfq, D_, HID_);
    // final LN2 -> reuse Xqb2 slot (dead after out-proj)
    ln_kernel<<<MQ_, 256, 0, stream>>>(Yfq, ln2_g + (size_t)l*D_, ln2_b + (size_t)l*D_, Xqb2);
  }

  head_kernel<<<MQ_, 64, 0, stream>>>(Xqb2, W_head, b_head, out);
}

// Round 15
// 1725.439 us; speedup vs baseline: 1.0487x; 1.0487x over previous
//
#include <hip/hip_runtime.h>

#define B_   16
#define C_   1024
#define Q_   128
#define S_   1152
#define D_   512
#define H_   8
#define HID_ 2048
#define L_   6
#define M_   (B_*S_)   // 18432 tokens
#define MQ_  (B_*Q_)   // 2048 query tokens
#define QSC_ 0.18033688011f   // 0.125 * log2(e): folds 1/sqrt(64) and 1/ln2 into Q

typedef short bf16x8 __attribute__((ext_vector_type(8)));
typedef float f32x4  __attribute__((ext_vector_type(4)));
#define MFMA16(a,b,c) __builtin_amdgcn_mfma_f32_16x16x32_bf16(a,b,c,0,0,0)

__device__ __forceinline__ unsigned short f2b(float f){
  union { float f; unsigned u; } v; v.f = f;
  return (unsigned short)((v.u + 0x7FFF + ((v.u >> 16) & 1)) >> 16);  // RNE
}
__device__ __forceinline__ float b2f(unsigned short u){
  return __uint_as_float((unsigned)u << 16);
}
__device__ __forceinline__ void gload16(const void* g, void* l){
  __builtin_amdgcn_global_load_lds((const __attribute__((address_space(1))) void*)g,
                                   (__attribute__((address_space(3))) void*)l, 16, 0, 0);
}
__device__ __forceinline__ float waveSum(float v){
  #pragma unroll
  for (int o = 32; o > 0; o >>= 1) v += __shfl_down(v, o, 64);
  return v;
}

// ---------------- fp32 -> bf16 weight conversion ----------------------------------
__global__ __launch_bounds__(256) void f2b_kernel(
    const float* __restrict__ in, unsigned short* __restrict__ out, int n4)
{
  int i = blockIdx.x*256 + threadIdx.x;
  for (; i < n4; i += gridDim.x*256) {
    float4 v = ((const float4*)in)[i];
    ushort4 o = { f2b(v.x), f2b(v.y), f2b(v.z), f2b(v.w) };
    ((ushort4*)out)[i] = o;
  }
}

// ---------------- in_proj_w -> bf16 with Q-rows pre-scaled by QSC_ -----------------
__global__ __launch_bounds__(256) void f2bq_kernel(
    const float* __restrict__ in, unsigned short* __restrict__ out, int n4)
{
  int i = blockIdx.x*256 + threadIdx.x;
  for (; i < n4; i += gridDim.x*256) {
    const int row = (i >> 7) % 1536;          // 128 float4 per 512-col row
    const float s = (row < 512) ? QSC_ : 1.f;
    float4 v = ((const float4*)in)[i];
    ushort4 o = { f2b(v.x*s), f2b(v.y*s), f2b(v.z*s), f2b(v.w*s) };
    ((ushort4*)out)[i] = o;
  }
}

// ---------------- in_proj_b scaled copy (Q part * QSC_) ----------------------------
__global__ __launch_bounds__(256) void sbias_kernel(
    const float* __restrict__ in, float* __restrict__ out)
{
  int idx = blockIdx.x*256 + threadIdx.x;     // L_*1536 = 9216
  if (idx < L_*1536) {
    int j = idx % 1536;
    out[idx] = in[idx] * (j < 512 ? QSC_ : 1.f);
  }
}

// ---------------- pack XY [M,128] bf16: x | y/0 | 1 | isq | zeros ------------------
__global__ __launch_bounds__(256) void packxy_kernel(
    const float* __restrict__ x_c, const float* __restrict__ y_c,
    const float* __restrict__ x_q, unsigned short* __restrict__ XY)
{
  int idx = blockIdx.x*256 + threadIdx.x;
  const int n = M_*128;
  for (; idx < n; idx += gridDim.x*256) {
    int row = idx >> 7, col = idx & 127;
    int bb = row / S_, s = row % S_;
    float v;
    if (col < 64) {
      v = (s < C_) ? x_c[((size_t)bb*C_ + s)*64 + col]
                   : x_q[((size_t)bb*Q_ + (s - C_))*64 + col];
    } else if (col < 96) {
      v = (s < C_) ? y_c[((size_t)bb*C_ + s)*32 + (col - 64)] : 0.f;
    } else if (col == 96) {
      v = 1.f;
    } else if (col == 97) {
      v = (s >= C_) ? 1.f : 0.f;
    } else v = 0.f;
    XY[idx] = f2b(v);
  }
}

// ---------------- build Wemb [512][128] bf16 (W_val^T | b_val | q_emb | 0) ---------
__global__ __launch_bounds__(256) void wemb_kernel(
    const float* __restrict__ W_val, const float* __restrict__ b_val,
    const float* __restrict__ q_emb, unsigned short* __restrict__ Wemb)
{
  int idx = blockIdx.x*256 + threadIdx.x;   // 512*128 = 65536 = 256*256
  int nn = idx >> 7, k = idx & 127;
  float v;
  if (k < 96)       v = W_val[k*D_ + nn];
  else if (k == 96) v = b_val[nn];
  else if (k == 97) v = q_emb[nn];
  else              v = 0.f;
  Wemb[idx] = f2b(v);
}

// ---------------- gather query rows (bf16) -> compact [MQ_,512] --------------------
__global__ __launch_bounds__(256) void gatherq_kernel(
    const unsigned short* __restrict__ X, unsigned short* __restrict__ Xq)
{
  int row = blockIdx.x;                 // 0..MQ_-1
  int bb = row >> 7, qi = row & 127;
  const unsigned short* src = X + ((size_t)bb*S_ + C_ + qi)*D_;
  unsigned short* dst = Xq + (size_t)row*D_;
  int tid = threadIdx.x;
  dst[tid] = src[tid];
  dst[tid + 256] = src[tid + 256];
}

// T2 swizzle: LDS slot (row, c) holds global chunk c ^ sw(row); linear gload_lds
// dest + pre-swizzled SOURCE + swizzled READ. sw period 8 in row (64 ≡ 0 mod 8,
// so the +64-row staging call shares the per-lane offset).
#define SWZ(row) (((row) >> 1) & 3)

// ---------------- bf16 MFMA GEMM, 2-phase double-buffered, 128x128 tile ------------
// BOUT: 0 = f32 out, 1 = bf16 out.
template<int RELU, int BOUT>
__global__ __launch_bounds__(256) void bgemm_kernel(
    const unsigned short* __restrict__ A, const unsigned short* __restrict__ W,
    const float* __restrict__ bias,
    float* __restrict__ Cf, unsigned short* __restrict__ Cb, int Nn, int Kk)
{
  __shared__ short As[2][4096];     // [buf][128][32] bf16
  __shared__ short Bs[2][4096];
  int lin = blockIdx.y * gridDim.x + blockIdx.x;
  const int nwg = gridDim.x * gridDim.y;
  const int cpx = nwg >> 3;
  lin = (lin & 7) * cpx + (lin >> 3);
  const int bm = (lin / gridDim.x) * 128, bn = (lin % gridDim.x) * 128;

  const int tid = threadIdx.x;
  const int w = tid >> 6, lane = tid & 63, l15 = lane & 15, l4 = lane >> 4;
  const int wm = w >> 1, wn = w & 1;
  f32x4 acc[4][4] = {};
  const size_t strA = (size_t)Kk * 2;          // bytes per row
  const char* Abase = (const char*)A + (size_t)bm * strA;
  const char* Wbase = (const char*)W + (size_t)bn * strA;
  const int srow = tid >> 2;
  const int schunk = (tid & 3) ^ SWZ(srow);    // pre-swizzled source chunk
  const size_t soff = (size_t)srow * strA + (size_t)(schunk * 16);
  const int ldsOff = w * 1024;

#define STAGEK(K0, BUF) do { \
    const char* a0_ = Abase + soff + (size_t)(K0)*2; \
    const char* b0_ = Wbase + soff + (size_t)(K0)*2; \
    char* la_ = (char*)As + (BUF)*8192 + ldsOff; \
    char* lb_ = (char*)Bs + (BUF)*8192 + ldsOff; \
    gload16(a0_,            la_); \
    gload16(a0_ + 64*strA,  la_ + 4096); \
    gload16(b0_,            lb_); \
    gload16(b0_ + 64*strA,  lb_ + 4096); \
  } while(0)

  STAGEK(0, 0);
  const int nk = Kk >> 5;
  for (int t = 0; t < nk; t++) {
    __syncthreads();                       // buf[t&1] staged; prior reads done
    if (t + 1 < nk) STAGEK((t+1)*32, (t+1)&1);   // prefetch under this tile's MFMAs
    const short* AsC = (const short*)As + (t&1)*4096;
    const short* BsC = (const short*)Bs + (t&1)*4096;
    bf16x8 af[4], bfr[4];
    #pragma unroll
    for (int mf = 0; mf < 4; mf++) {
      const int ar = wm*64 + mf*16 + l15;
      af[mf] = *(const bf16x8*)(AsC + ar*32 + (l4 ^ SWZ(ar))*8);
    }
    #pragma unroll
    for (int nf = 0; nf < 4; nf++) {
      const int br = wn*64 + nf*16 + l15;
      bfr[nf] = *(const bf16x8*)(BsC + br*32 + (l4 ^ SWZ(br))*8);
    }
    #pragma unroll
    for (int mf = 0; mf < 4; mf++)
      #pragma unroll
      for (int nf = 0; nf < 4; nf++)
        acc[mf][nf] = MFMA16(af[mf], bfr[nf], acc[mf][nf]);
  }
#undef STAGEK

  #pragma unroll
  for (int mf = 0; mf < 4; mf++) {
    #pragma unroll
    for (int nf = 0; nf < 4; nf++) {
      const int ccol = bn + wn*64 + nf*16 + l15;
      const float bv = bias[ccol];
      #pragma unroll
      for (int r = 0; r < 4; r++) {
        const int rrow = bm + wm*64 + mf*16 + l4*4 + r;
        float o = acc[mf][nf][r] + bv;
        if (RELU) o = fmaxf(o, 0.f);
        if (BOUT == 1) Cb[(size_t)rrow*Nn + ccol] = f2b(o);
        else           Cf[(size_t)rrow*Nn + ccol] = o;
      }
    }
  }
}

// ---------------- bf16 MFMA GEMM, 128x64 tile, 3-buffer counted-vmcnt + T2 swizzle -
// bf16 residual, f32 out. (out-proj / FFN2 / compact layer-6 path)
__global__ __launch_bounds__(256) void bgemm64_kernel(
    const unsigned short* __restrict__ A, const unsigned short* __restrict__ W,
    const float* __restrict__ bias, const unsigned short* __restrict__ Rsd,
    float* __restrict__ Cf, int Nn, int Kk)
{
  __shared__ short As[3][4096];     // [buf][128][32] bf16
  __shared__ short Bs[3][2048];     // [buf][64][32]  bf16
  int lin = blockIdx.y * gridDim.x + blockIdx.x;
  const int nwg = gridDim.x * gridDim.y;
  const int cpx = nwg >> 3;
  lin = (lin & 7) * cpx + (lin >> 3);
  const int bm = (lin / gridDim.x) * 128, bn = (lin % gridDim.x) * 64;

  const int tid = threadIdx.x;
  const int w = tid >> 6, lane = tid & 63, l15 = lane & 15, l4 = lane >> 4;
  f32x4 acc[2][4] = {};
  const size_t strA = (size_t)Kk * 2;
  const char* Abase = (const char*)A + (size_t)bm * strA;
  const char* Wbase = (const char*)W + (size_t)bn * strA;
  const int srow = tid >> 2;
  const int schunk = (tid & 3) ^ SWZ(srow);
  const size_t soff = (size_t)srow * strA + (size_t)(schunk * 16);
  const int ldsOff = w * 1024;

#define STAGEK64(K0, BUF) do { \
    const char* a0_ = Abase + soff + (size_t)(K0)*2; \
    const char* b0_ = Wbase + soff + (size_t)(K0)*2; \
    char* la_ = (char*)As + (BUF)*8192 + ldsOff; \
    char* lb_ = (char*)Bs + (BUF)*4096 + ldsOff; \
    gload16(a0_,            la_); \
    gload16(a0_ + 64*strA,  la_ + 4096); \
    gload16(b0_,            lb_); \
  } while(0)

  const int nk = Kk >> 5;
  STAGEK64(0, 0);
  STAGEK64(32, 1);
  int rb = 0;
  for (int t = 0; t < nk; t++) {
    if (t + 1 < nk) asm volatile("s_waitcnt vmcnt(3)" ::: "memory");
    else            asm volatile("s_waitcnt vmcnt(0)" ::: "memory");
    __builtin_amdgcn_s_barrier();
    __builtin_amdgcn_sched_barrier(0);
    if (t + 2 < nk) {
      int wbuf = rb + 2; if (wbuf >= 3) wbuf -= 3;
      STAGEK64((t+2)*32, wbuf);
    }
    const short* AsC = (const short*)As + rb*4096;
    const short* BsC = (const short*)Bs + rb*2048;
    bf16x8 af[2], bfr[4];
    #pragma unroll
    for (int mf = 0; mf < 2; mf++) {
      const int ar = w*32 + mf*16 + l15;
      af[mf] = *(const bf16x8*)(AsC + ar*32 + (l4 ^ SWZ(ar))*8);
    }
    #pragma unroll
    for (int nf = 0; nf < 4; nf++) {
      const int br = nf*16 + l15;
      bfr[nf] = *(const bf16x8*)(BsC + br*32 + (l4 ^ SWZ(br))*8);
    }
    #pragma unroll
    for (int mf = 0; mf < 2; mf++)
      #pragma unroll
      for (int nf = 0; nf < 4; nf++)
        acc[mf][nf] = MFMA16(af[mf], bfr[nf], acc[mf][nf]);
    rb++; if (rb >= 3) rb = 0;
  }
#undef STAGEK64

  #pragma unroll
  for (int mf = 0; mf < 2; mf++) {
    #pragma unroll
    for (int nf = 0; nf < 4; nf++) {
      const int ccol = bn + nf*16 + l15;
      const float bv = bias[ccol];
      #pragma unroll
      for (int r = 0; r < 4; r++) {
        const int rrow = bm + w*32 + mf*16 + l4*4 + r;
        float o = acc[mf][nf][r] + bv + b2f(Rsd[(size_t)rrow*Nn + ccol]);
        Cf[(size_t)rrow*Nn + ccol] = o;
      }
    }
  }
}

// ---------------- MFMA flash attention, QBLK=64, base-2 softmax, no running max ----
// Scores are log2-domain (Q pre-scaled); |s| << 127 so exp2(s) cannot overflow ->
// running-max tracking removed entirely: P = exp2(s), l = sum(P), divide at end.
__global__ __launch_bounds__(256) void mattn_kernel(
    const unsigned short* __restrict__ QKV, unsigned short* __restrict__ Ctx,
    int nqt, int qoff, int orows)
{
  __shared__ short Ks[64*72];      // [key][hd], 144B row stride
  __shared__ short Vt[64*72];      // [hd][key] transposed, slot-XOR swizzled
  __shared__ short Ps[4*16*72];    // per-wave P tile [q][key]
  int bid = blockIdx.x;
  const int nwg = gridDim.x;                 // always % 8 == 0 (2304 or 256)
  bid = (bid & 7) * (nwg >> 3) + (bid >> 3);
  const int qt = bid % nqt;
  const int h  = (bid / nqt) % H_;
  const int bb = bid / (nqt*H_);
  const int tid = threadIdx.x;
  const int w = tid >> 6, lane = tid & 63, l15 = lane & 15, l4 = lane >> 4;

  const size_t rowQ = (size_t)bb*S_ + qoff + (size_t)qt*64 + w*16 + l15;
  const unsigned short* qp = QKV + rowQ*1536 + h*64;
  const bf16x8 qf0 = *(const bf16x8*)(qp + l4*8);
  const bf16x8 qf1 = *(const bf16x8*)(qp + 32 + l4*8);

  const unsigned short* Kg = QKV + (size_t)bb*S_*1536 + 512 + h*64;
  const unsigned short* Vg = Kg + 512;

  f32x4 ctx[4] = {};
  f32x4 lacc = {};                 // row-sum accumulator (all cols identical)

  const bf16x8 onesv = {(short)0x3F80,(short)0x3F80,(short)0x3F80,(short)0x3F80,
                        (short)0x3F80,(short)0x3F80,(short)0x3F80,(short)0x3F80};

  char* PsW = (char*)Ps + w*2304;

  const int skey = tid >> 3, shc = tid & 7;
  const int vp   = tid >> 3, vhc = tid & 7;

  const unsigned short* gK = Kg + (size_t)skey*1536 + shc*8;
  const unsigned short* gV = Vg + (size_t)(2*vp)*1536 + vhc*8;
  bf16x8 k0v = *(const bf16x8*)gK;
  bf16x8 k1v = *(const bf16x8*)(gK + 32*1536);
  bf16x8 c0  = *(const bf16x8*)gV;
  bf16x8 c1  = *(const bf16x8*)(gV + 1536);

  for (int kt = 0; kt < 16; kt++) {
    __syncthreads();
    *(bf16x8*)((char*)Ks + skey*144      + shc*16) = k0v;
    *(bf16x8*)((char*)Ks + (skey+32)*144 + shc*16) = k1v;
    #pragma unroll
    for (int j = 0; j < 8; j++) {
      const int hd = vhc*8 + j;
      unsigned int val = (unsigned int)(unsigned short)c0[j]
                       | ((unsigned int)(unsigned short)c1[j] << 16);
      *(unsigned int*)((char*)Vt + hd*144 + ((4*vp) ^ (vhc<<4))) = val;
    }
    __syncthreads();
    // T14: issue next tile's global loads now; latency hides under compute
    if (kt < 15) {
      const unsigned short* nK = gK + (size_t)(kt+1)*98304;
      const unsigned short* nV = gV + (size_t)(kt+1)*98304;
      k0v = *(const bf16x8*)nK;
      k1v = *(const bf16x8*)(nK + 32*1536);
      c0  = *(const bf16x8*)nV;
      c1  = *(const bf16x8*)(nV + 1536);
    }

    // S = Q K^T  (log2-domain scores; Q pre-scaled)
    f32x4 sac[4] = {};
    __builtin_amdgcn_s_setprio(1);
    #pragma unroll
    for (int nf = 0; nf < 4; nf++) {
      const char* kb = (char*)Ks + (nf*16 + l15)*144 + l4*16;
      bf16x8 b0 = *(const bf16x8*)kb;
      bf16x8 b1 = *(const bf16x8*)(kb + 64);
      sac[nf] = MFMA16(qf0, b0, sac[nf]);
      sac[nf] = MFMA16(qf1, b1, sac[nf]);
    }
    __builtin_amdgcn_s_setprio(0);

    // P = exp2(s) -> LDS truncated bf16 (no max subtraction needed)
    #pragma unroll
    for (int r = 0; r < 4; r++) {
      unsigned short* pw = (unsigned short*)(PsW + (l4*4 + r)*144);
      pw[ 0 + l15] = (unsigned short)(__float_as_uint(__builtin_amdgcn_exp2f(sac[0][r])) >> 16);
      pw[16 + l15] = (unsigned short)(__float_as_uint(__builtin_amdgcn_exp2f(sac[1][r])) >> 16);
      pw[32 + l15] = (unsigned short)(__float_as_uint(__builtin_amdgcn_exp2f(sac[2][r])) >> 16);
      pw[48 + l15] = (unsigned short)(__float_as_uint(__builtin_amdgcn_exp2f(sac[3][r])) >> 16);
    }

    // PV: ctx += P(16xkeys) * V(keys x 64hd); l += P * ones
    const char* pb = PsW + l15*144 + l4*16;
    const bf16x8 pf0 = *(const bf16x8*)pb;
    const bf16x8 pf1 = *(const bf16x8*)(pb + 64);
    __builtin_amdgcn_s_setprio(1);
    lacc = MFMA16(pf0, onesv, lacc);
    lacc = MFMA16(pf1, onesv, lacc);
    #pragma unroll
    for (int hf = 0; hf < 4; hf++) {
      const int hd = hf*16 + l15;
      const int hc = (hd >> 3) & 7;
      const char* vb = (char*)Vt + hd*144;
      bf16x8 v0 = *(const bf16x8*)(vb + ((l4*16)     ^ (hc<<4)));
      bf16x8 v1 = *(const bf16x8*)(vb + (((l4+4)*16) ^ (hc<<4)));
      ctx[hf] = MFMA16(pf0, v0, ctx[hf]);
      ctx[hf] = MFMA16(pf1, v1, ctx[hf]);
    }
    __builtin_amdgcn_s_setprio(0);
  }

  // epilogue: divide by l, store bf16 ctx
  #pragma unroll
  for (int r = 0; r < 4; r++) {
    const float invl = 1.0f / lacc[r];
    const size_t row = (size_t)bb*orows + (size_t)qt*64 + w*16 + l4*4 + r;
    unsigned short* op = Ctx + row*512 + h*64;
    op[ 0 + l15] = f2b(ctx[0][r]*invl);
    op[16 + l15] = f2b(ctx[1][r]*invl);
    op[32 + l15] = f2b(ctx[2][r]*invl);
    op[48 + l15] = f2b(ctx[3][r]*invl);
  }
}

// ---------------- row LayerNorm over D=512: fp32 in, bf16 out ----------------------
__global__ __launch_bounds__(256) void ln_kernel(
    const float* __restrict__ Yin, const float* __restrict__ g, const float* __restrict__ b,
    unsigned short* __restrict__ Xb)
{
  int row = blockIdx.x, tid = threadIdx.x;
  const float* yr = Yin + (size_t)row*D_;
  float v0 = yr[tid], v1 = yr[tid + 256];
  __shared__ float red[4];
  float s = waveSum(v0 + v1);
  if ((tid & 63) == 0) red[tid >> 6] = s;
  __syncthreads();
  float mu = (red[0] + red[1] + red[2] + red[3]) * (1.f/512.f);
  __syncthreads();
  float d0 = v0 - mu, d1 = v1 - mu;
  float ss = waveSum(d0*d0 + d1*d1);
  if ((tid & 63) == 0) red[tid >> 6] = ss;
  __syncthreads();
  float inv = rsqrtf((red[0] + red[1] + red[2] + red[3]) * (1.f/512.f) + 1e-5f);
  Xb[(size_t)row*D_ + tid]       = f2b(d0 * inv * g[tid]       + b[tid]);
  Xb[(size_t)row*D_ + tid + 256] = f2b(d1 * inv * g[tid + 256] + b[tid + 256]);
}

// ---------------- head: Xq[row](bf16) @ W_head[512,32] + b_head --------------------
__global__ __launch_bounds__(64) void head_kernel(
    const unsigned short* __restrict__ Xq, const float* __restrict__ W_head,
    const float* __restrict__ b_head, float* __restrict__ out)
{
  int row = blockIdx.x;            // 0..MQ_-1
  const unsigned short* xr = Xq + (size_t)row*D_;
  __shared__ float xs[512];
  int tid = threadIdx.x;
  for (int i = tid; i < 512; i += 64) xs[i] = b2f(xr[i]);
  __syncthreads();
  if (tid < 32) {
    float acc = b_head[tid];
    #pragma unroll 8
    for (int k = 0; k < 512; k++) acc += xs[k] * W_head[k*32 + tid];
    out[(size_t)row*32 + tid] = acc;
  }
}

extern "C" void kernel_launch(void* const* d_in, const int* in_sizes, int n_in,
                              void* d_out, int out_size, void* d_ws, size_t ws_size,
                              hipStream_t stream)
{
  const float* x_c      = (const float*)d_in[0];
  const float* y_c      = (const float*)d_in[1];
  const float* x_q      = (const float*)d_in[2];
  const float* W_val    = (const float*)d_in[3];
  const float* b_val    = (const float*)d_in[4];
  const float* q_emb    = (const float*)d_in[5];
  const float* in_proj_w= (const float*)d_in[6];
  const float* in_proj_b= (const float*)d_in[7];
  const float* out_w    = (const float*)d_in[8];
  const float* out_b    = (const float*)d_in[9];
  const float* ln1_g    = (const float*)d_in[10];
  const float* ln1_b    = (const float*)d_in[11];
  const float* lin1_w   = (const float*)d_in[12];
  const float* lin1_b   = (const float*)d_in[13];
  const float* lin2_w   = (const float*)d_in[14];
  const float* lin2_b   = (const float*)d_in[15];
  const float* ln2_g    = (const float*)d_in[16];
  const float* ln2_b    = (const float*)d_in[17];
  const float* W_head   = (const float*)d_in[18];
  const float* b_head   = (const float*)d_in[19];
  float* out = (float*)d_out;

  // workspace layout (~250 MB); residual stream is bf16 (Xb1/Xb2), Yf = pre-LN fp32
  char* p = (char*)d_ws;
  float* Yf = (float*)p;                     p += (size_t)M_*D_*4;    // GEMM+res out
  unsigned short* hid  = (unsigned short*)p; p += (size_t)M_*HID_*2;
  unsigned short* Xb2  = (unsigned short*)p; p += (size_t)M_*D_*2;    // ln2/embed out
  unsigned short* qkv  = (unsigned short*)p; p += (size_t)M_*3*D_*2;
  unsigned short* Xb1  = qkv;                                          // alias: ln1 out (disjoint live range)
  unsigned short* ctxb = (unsigned short*)p; p += (size_t)M_*D_*2;
  unsigned short* ipwB = (unsigned short*)p; p += (size_t)L_*3*D_*D_*2;
  unsigned short* owB  = (unsigned short*)p; p += (size_t)L_*D_*D_*2;
  unsigned short* w1B  = (unsigned short*)p; p += (size_t)L_*HID_*D_*2;
  unsigned short* w2B  = (unsigned short*)p; p += (size_t)L_*D_*HID_*2;
  unsigned short* XYb  = (unsigned short*)p; p += (size_t)M_*128*2;
  unsigned short* Wemb = (unsigned short*)p; p += (size_t)D_*128*2;
  float* zbias         = (float*)p;          p += 2048*4;
  float* qkvbias       = (float*)p;          p += L_*1536*4;

  // compact layer-6 buffers (alias XYb region, idle post-embed)
  unsigned short* ctxq  = ctxb;                                   // [MQ_,512]
  float*          Yfq   = Yf;                                     // [MQ_,512] fp32
  unsigned short* hidq  = hid;                                    // [MQ_,2048]
  unsigned short* Xqb2  = XYb;                                    // gathered residual
  unsigned short* Xqb1  = XYb + (size_t)MQ_*D_;                   // ln1 out

  (void)hipMemsetAsync(zbias, 0, 2048*4, stream);

  // convert weights to bf16 (Q rows of in_proj pre-scaled by 0.125*log2e)
  f2bq_kernel<<<512, 256, 0, stream>>>(in_proj_w, ipwB, L_*3*D_*D_/4);
  sbias_kernel<<<36, 256, 0, stream>>>(in_proj_b, qkvbias);
  f2b_kernel<<<512, 256, 0, stream>>>(out_w,     owB,  L_*D_*D_/4);
  f2b_kernel<<<512, 256, 0, stream>>>(lin1_w,    w1B,  L_*HID_*D_/4);
  f2b_kernel<<<512, 256, 0, stream>>>(lin2_w,    w2B,  L_*D_*HID_/4);
  wemb_kernel<<<256, 256, 0, stream>>>(W_val, b_val, q_emb, Wemb);
  packxy_kernel<<<1024, 256, 0, stream>>>(x_c, y_c, x_q, XYb);

  // embedding as GEMM (bf16 out -> Xb2)
  bgemm_kernel<0,1><<<dim3(4, 144), 256, 0, stream>>>(
      XYb, Wemb, zbias, nullptr, Xb2, D_, 128);

  for (int l = 0; l < L_ - 1; l++) {
    // QKV projection (bf16 out, scaled Q)
    bgemm_kernel<0,1><<<dim3(12, 144), 256, 0, stream>>>(
        Xb2, ipwB + (size_t)l*3*D_*D_, qkvbias + (size_t)l*3*D_,
        nullptr, qkv, 3*D_, D_);
    // attention (full: 18 q-tiles per (b,h))
    mattn_kernel<<<B_*H_*18, 256, 0, stream>>>(qkv, ctxb, 18, 0, S_);
    // out-proj + bf16 residual(Xb2) -> Yf fp32
    bgemm64_kernel<<<dim3(8, 144), 256, 0, stream>>>(
        ctxb, owB + (size_t)l*D_*D_, out_b + (size_t)l*D_, Xb2, Yf, D_, D_);
    ln_kernel<<<M_, 256, 0, stream>>>(Yf, ln1_g + (size_t)l*D_, ln1_b + (size_t)l*D_, Xb1);
    // FFN1 (relu, bf16 out)
    bgemm_kernel<1,1><<<dim3(16, 144), 256, 0, stream>>>(
        Xb1, w1B + (size_t)l*HID_*D_, lin1_b + (size_t)l*HID_,
        nullptr, hid, HID_, D_);
    // FFN2 + bf16 residual(Xb1) -> Yf
    bgemm64_kernel<<<dim3(8, 144), 256, 0, stream>>>(
        hid, w2B + (size_t)l*D_*HID_, lin2_b + (size_t)l*D_, Xb1, Yf, D_, HID_);
    ln_kernel<<<M_, 256, 0, stream>>>(Yf, ln2_g + (size_t)l*D_, ln2_b + (size_t)l*D_, Xb2);
  }

  // ---------- layer 6 (l = L_-1): only query rows reach the head ----------
  {
    const int l = L_ - 1;
    bgemm_kernel<0,1><<<dim3(12, 144), 256, 0, stream>>>(
        Xb2, ipwB + (size_t)l*3*D_*D_, qkvbias + (size_t)l*3*D_,
        nullptr, qkv, 3*D_, D_);
    // attention only for the 2 query q-tiles per (b,h); compact output [MQ_,512]
    mattn_kernel<<<B_*H_*2, 256, 0, stream>>>(qkv, ctxq, 2, C_, Q_);
    // gather query rows of Xb2 -> Xqb2 (bf16)
    gatherq_kernel<<<MQ_, 256, 0, stream>>>(Xb2, Xqb2);
    // out-proj + residual(Xqb2) -> Yfq (M = 2048)
    bgemm64_kernel<<<dim3(8, 16), 256, 0, stream>>>(
        ctxq, owB + (size_t)l*D_*D_, out_b + (size_t)l*D_, Xqb2, Yfq, D_, D_);
    ln_kernel<<<MQ_, 256, 0, stream>>>(Yfq, ln1_g + (size_t)l*D_, ln1_b + (size_t)l*D_, Xqb1);
    // FFN1 (relu) compact
    bgemm_kernel<1,1><<<dim3(16, 16), 256, 0, stream>>>(
        Xqb1, w1B + (size_t)l*HID_*D_, lin1_b + (size_t)l*HID_,
        nullptr, hidq, HID_, D_);
    // FFN2 + residual(Xqb1) -> Yfq
    bgemm64_kernel<<<dim3(8, 16), 256, 0, stream>>>(
        hidq, w2B + (size_t)l*D_*HID_, lin2_b + (size_t)l*D_, Xqb1, Yfq, D_, HID_);
    // final LN2 -> reuse Xqb2 slot (dead after out-proj)
    ln_kernel<<<MQ_, 256, 0, stream>>>(Yfq, ln2_g + (size_t)l*D_, ln2_b + (size_t)l*D_, Xqb2);
  }

  head_kernel<<<MQ_, 64, 0, stream>>>(Xqb2, W_head, b_head, out);
}

// Round 16
// 1584.841 us; speedup vs baseline: 1.1417x; 1.0887x over previous
//
#include <hip/hip_runtime.h>

#define B_   16
#define C_   1024
#define Q_   128
#define S_   1152
#define D_   512
#define H_   8
#define HID_ 2048
#define L_   6
#define M_   (B_*S_)   // 18432 tokens
#define MQ_  (B_*Q_)   // 2048 query tokens
#define QSC_ 0.18033688011f   // 0.125 * log2(e): folds 1/sqrt(64) and 1/ln2 into Q

typedef short bf16x8 __attribute__((ext_vector_type(8)));
typedef float f32x4  __attribute__((ext_vector_type(4)));
#define MFMA16(a,b,c) __builtin_amdgcn_mfma_f32_16x16x32_bf16(a,b,c,0,0,0)

__device__ __forceinline__ unsigned short f2b(float f){
  union { float f; unsigned u; } v; v.f = f;
  return (unsigned short)((v.u + 0x7FFF + ((v.u >> 16) & 1)) >> 16);  // RNE
}
__device__ __forceinline__ float b2f(unsigned short u){
  return __uint_as_float((unsigned)u << 16);
}
__device__ __forceinline__ void gload16(const void* g, void* l){
  __builtin_amdgcn_global_load_lds((const __attribute__((address_space(1))) void*)g,
                                   (__attribute__((address_space(3))) void*)l, 16, 0, 0);
}
__device__ __forceinline__ float waveSum(float v){
  #pragma unroll
  for (int o = 32; o > 0; o >>= 1) v += __shfl_down(v, o, 64);
  return v;
}

// ---------------- fp32 -> bf16 weight conversion ----------------------------------
__global__ __launch_bounds__(256) void f2b_kernel(
    const float* __restrict__ in, unsigned short* __restrict__ out, int n4)
{
  int i = blockIdx.x*256 + threadIdx.x;
  for (; i < n4; i += gridDim.x*256) {
    float4 v = ((const float4*)in)[i];
    ushort4 o = { f2b(v.x), f2b(v.y), f2b(v.z), f2b(v.w) };
    ((ushort4*)out)[i] = o;
  }
}

// ---------------- in_proj_w -> bf16 with Q-rows pre-scaled by QSC_ -----------------
__global__ __launch_bounds__(256) void f2bq_kernel(
    const float* __restrict__ in, unsigned short* __restrict__ out, int n4)
{
  int i = blockIdx.x*256 + threadIdx.x;
  for (; i < n4; i += gridDim.x*256) {
    const int row = (i >> 7) % 1536;          // 128 float4 per 512-col row
    const float s = (row < 512) ? QSC_ : 1.f;
    float4 v = ((const float4*)in)[i];
    ushort4 o = { f2b(v.x*s), f2b(v.y*s), f2b(v.z*s), f2b(v.w*s) };
    ((ushort4*)out)[i] = o;
  }
}

// ---------------- in_proj_b scaled copy (Q part * QSC_) ----------------------------
__global__ __launch_bounds__(256) void sbias_kernel(
    const float* __restrict__ in, float* __restrict__ out)
{
  int idx = blockIdx.x*256 + threadIdx.x;     // L_*1536 = 9216
  if (idx < L_*1536) {
    int j = idx % 1536;
    out[idx] = in[idx] * (j < 512 ? QSC_ : 1.f);
  }
}

// ---------------- pack XY [M,128] bf16: x | y/0 | 1 | isq | zeros ------------------
__global__ __launch_bounds__(256) void packxy_kernel(
    const float* __restrict__ x_c, const float* __restrict__ y_c,
    const float* __restrict__ x_q, unsigned short* __restrict__ XY)
{
  int idx = blockIdx.x*256 + threadIdx.x;
  const int n = M_*128;
  for (; idx < n; idx += gridDim.x*256) {
    int row = idx >> 7, col = idx & 127;
    int bb = row / S_, s = row % S_;
    float v;
    if (col < 64) {
      v = (s < C_) ? x_c[((size_t)bb*C_ + s)*64 + col]
                   : x_q[((size_t)bb*Q_ + (s - C_))*64 + col];
    } else if (col < 96) {
      v = (s < C_) ? y_c[((size_t)bb*C_ + s)*32 + (col - 64)] : 0.f;
    } else if (col == 96) {
      v = 1.f;
    } else if (col == 97) {
      v = (s >= C_) ? 1.f : 0.f;
    } else v = 0.f;
    XY[idx] = f2b(v);
  }
}

// ---------------- build Wemb [512][128] bf16 (W_val^T | b_val | q_emb | 0) ---------
__global__ __launch_bounds__(256) void wemb_kernel(
    const float* __restrict__ W_val, const float* __restrict__ b_val,
    const float* __restrict__ q_emb, unsigned short* __restrict__ Wemb)
{
  int idx = blockIdx.x*256 + threadIdx.x;   // 512*128 = 65536 = 256*256
  int nn = idx >> 7, k = idx & 127;
  float v;
  if (k < 96)       v = W_val[k*D_ + nn];
  else if (k == 96) v = b_val[nn];
  else if (k == 97) v = q_emb[nn];
  else              v = 0.f;
  Wemb[idx] = f2b(v);
}

// ---------------- gather query rows (bf16) -> compact [MQ_,512] --------------------
__global__ __launch_bounds__(256) void gatherq_kernel(
    const unsigned short* __restrict__ X, unsigned short* __restrict__ Xq)
{
  int row = blockIdx.x;                 // 0..MQ_-1
  int bb = row >> 7, qi = row & 127;
  const unsigned short* src = X + ((size_t)bb*S_ + C_ + qi)*D_;
  unsigned short* dst = Xq + (size_t)row*D_;
  int tid = threadIdx.x;
  dst[tid] = src[tid];
  dst[tid + 256] = src[tid + 256];
}

// T2 swizzle (BK=32 kernels): LDS slot (row, c in 0..3) holds global chunk c ^ SWZ(row)
#define SWZ(row) (((row) >> 1) & 3)
// T2 swizzle (BK=64 kernel): 8 chunks of 16B per 128B row; slot c holds chunk c ^ (row&7)

// ---------------- bf16 MFMA GEMM, 2-phase double-buffered, 128x128 tile, BK=32 -----
// BOUT: 0 = f32 out, 1 = bf16 out.
template<int RELU, int BOUT>
__global__ __launch_bounds__(256) void bgemm_kernel(
    const unsigned short* __restrict__ A, const unsigned short* __restrict__ W,
    const float* __restrict__ bias,
    float* __restrict__ Cf, unsigned short* __restrict__ Cb, int Nn, int Kk)
{
  __shared__ short As[2][4096];     // [buf][128][32] bf16
  __shared__ short Bs[2][4096];
  int lin = blockIdx.y * gridDim.x + blockIdx.x;
  const int nwg = gridDim.x * gridDim.y;
  const int cpx = nwg >> 3;
  lin = (lin & 7) * cpx + (lin >> 3);
  const int bm = (lin / gridDim.x) * 128, bn = (lin % gridDim.x) * 128;

  const int tid = threadIdx.x;
  const int w = tid >> 6, lane = tid & 63, l15 = lane & 15, l4 = lane >> 4;
  const int wm = w >> 1, wn = w & 1;
  f32x4 acc[4][4] = {};
  const size_t strA = (size_t)Kk * 2;          // bytes per row
  const char* Abase = (const char*)A + (size_t)bm * strA;
  const char* Wbase = (const char*)W + (size_t)bn * strA;
  const int srow = tid >> 2;
  const int schunk = (tid & 3) ^ SWZ(srow);    // pre-swizzled source chunk
  const size_t soff = (size_t)srow * strA + (size_t)(schunk * 16);
  const int ldsOff = w * 1024;

#define STAGEK(K0, BUF) do { \
    const char* a0_ = Abase + soff + (size_t)(K0)*2; \
    const char* b0_ = Wbase + soff + (size_t)(K0)*2; \
    char* la_ = (char*)As + (BUF)*8192 + ldsOff; \
    char* lb_ = (char*)Bs + (BUF)*8192 + ldsOff; \
    gload16(a0_,            la_); \
    gload16(a0_ + 64*strA,  la_ + 4096); \
    gload16(b0_,            lb_); \
    gload16(b0_ + 64*strA,  lb_ + 4096); \
  } while(0)

  STAGEK(0, 0);
  const int nk = Kk >> 5;
  for (int t = 0; t < nk; t++) {
    __syncthreads();                       // buf[t&1] staged; prior reads done
    if (t + 1 < nk) STAGEK((t+1)*32, (t+1)&1);   // prefetch under this tile's MFMAs
    const short* AsC = (const short*)As + (t&1)*4096;
    const short* BsC = (const short*)Bs + (t&1)*4096;
    bf16x8 af[4], bfr[4];
    #pragma unroll
    for (int mf = 0; mf < 4; mf++) {
      const int ar = wm*64 + mf*16 + l15;
      af[mf] = *(const bf16x8*)(AsC + ar*32 + (l4 ^ SWZ(ar))*8);
    }
    #pragma unroll
    for (int nf = 0; nf < 4; nf++) {
      const int br = wn*64 + nf*16 + l15;
      bfr[nf] = *(const bf16x8*)(BsC + br*32 + (l4 ^ SWZ(br))*8);
    }
    #pragma unroll
    for (int mf = 0; mf < 4; mf++)
      #pragma unroll
      for (int nf = 0; nf < 4; nf++)
        acc[mf][nf] = MFMA16(af[mf], bfr[nf], acc[mf][nf]);
  }
#undef STAGEK

  #pragma unroll
  for (int mf = 0; mf < 4; mf++) {
    #pragma unroll
    for (int nf = 0; nf < 4; nf++) {
      const int ccol = bn + wn*64 + nf*16 + l15;
      const float bv = bias[ccol];
      #pragma unroll
      for (int r = 0; r < 4; r++) {
        const int rrow = bm + wm*64 + mf*16 + l4*4 + r;
        float o = acc[mf][nf][r] + bv;
        if (RELU) o = fmaxf(o, 0.f);
        if (BOUT == 1) Cb[(size_t)rrow*Nn + ccol] = f2b(o);
        else           Cf[(size_t)rrow*Nn + ccol] = o;
      }
    }
  }
}

// ---------------- bf16 MFMA GEMM, 128x64 tile, BK=64, 2-phase dbuf -----------------
// bf16 residual, f32 out. 16 MFMA / 12 ds_read per iter; 8-chunk XOR swizzle.
__global__ __launch_bounds__(256) void bgemm64_kernel(
    const unsigned short* __restrict__ A, const unsigned short* __restrict__ W,
    const float* __restrict__ bias, const unsigned short* __restrict__ Rsd,
    float* __restrict__ Cf, int Nn, int Kk)
{
  __shared__ short As[2][8192];     // [buf][128][64] bf16
  __shared__ short Bs[2][4096];     // [buf][64][64]  bf16
  int lin = blockIdx.y * gridDim.x + blockIdx.x;
  const int nwg = gridDim.x * gridDim.y;
  const int cpx = nwg >> 3;
  lin = (lin & 7) * cpx + (lin >> 3);
  const int bm = (lin / gridDim.x) * 128, bn = (lin % gridDim.x) * 64;

  const int tid = threadIdx.x;
  const int w = tid >> 6, lane = tid & 63, l15 = lane & 15, l4 = lane >> 4;
  f32x4 acc[2][4] = {};
  const size_t strA = (size_t)Kk * 2;
  const char* Abase = (const char*)A + (size_t)bm * strA;
  const char* Wbase = (const char*)W + (size_t)bn * strA;
  const int srow = tid >> 3;                   // 0..31 (32 rows per 4KB stage call)
  const int schunk = (tid & 7) ^ (srow & 7);   // pre-swizzled source chunk (16B)
  const size_t soff = (size_t)srow * strA + (size_t)(schunk * 16);
  const int ldsOff = w * 1024;

#define STG64(K0, BUF) do { \
    const char* a0_ = Abase + soff + (size_t)(K0)*2; \
    const char* b0_ = Wbase + soff + (size_t)(K0)*2; \
    char* la_ = (char*)As + (BUF)*16384 + ldsOff; \
    char* lb_ = (char*)Bs + (BUF)*8192  + ldsOff; \
    gload16(a0_,            la_); \
    gload16(a0_ + 32*strA,  la_ + 4096); \
    gload16(a0_ + 64*strA,  la_ + 8192); \
    gload16(a0_ + 96*strA,  la_ + 12288); \
    gload16(b0_,            lb_); \
    gload16(b0_ + 32*strA,  lb_ + 4096); \
  } while(0)

  STG64(0, 0);
  const int nk = Kk >> 6;
  for (int t = 0; t < nk; t++) {
    __syncthreads();                       // buf[t&1] staged; prior reads done
    if (t + 1 < nk) STG64((t+1)*64, (t+1)&1);
    const short* AsC = (const short*)As + (t&1)*8192;
    const short* BsC = (const short*)Bs + (t&1)*4096;
    bf16x8 af[2][2], bfr[4][2];
    #pragma unroll
    for (int mf = 0; mf < 2; mf++) {
      const int ar = w*32 + mf*16 + l15;
      #pragma unroll
      for (int ks = 0; ks < 2; ks++) {
        const int c = ks*4 + l4;
        af[mf][ks] = *(const bf16x8*)(AsC + ar*64 + (c ^ (ar & 7))*8);
      }
    }
    #pragma unroll
    for (int nf = 0; nf < 4; nf++) {
      const int br = nf*16 + l15;
      #pragma unroll
      for (int ks = 0; ks < 2; ks++) {
        const int c = ks*4 + l4;
        bfr[nf][ks] = *(const bf16x8*)(BsC + br*64 + (c ^ (br & 7))*8);
      }
    }
    #pragma unroll
    for (int ks = 0; ks < 2; ks++)
      #pragma unroll
      for (int mf = 0; mf < 2; mf++)
        #pragma unroll
        for (int nf = 0; nf < 4; nf++)
          acc[mf][nf] = MFMA16(af[mf][ks], bfr[nf][ks], acc[mf][nf]);
  }
#undef STG64

  #pragma unroll
  for (int mf = 0; mf < 2; mf++) {
    #pragma unroll
    for (int nf = 0; nf < 4; nf++) {
      const int ccol = bn + nf*16 + l15;
      const float bv = bias[ccol];
      #pragma unroll
      for (int r = 0; r < 4; r++) {
        const int rrow = bm + w*32 + mf*16 + l4*4 + r;
        float o = acc[mf][nf][r] + bv + b2f(Rsd[(size_t)rrow*Nn + ccol]);
        Cf[(size_t)rrow*Nn + ccol] = o;
      }
    }
  }
}

// ---------------- MFMA flash attention, QBLK=64, base-2 softmax, no running max ----
__global__ __launch_bounds__(256) void mattn_kernel(
    const unsigned short* __restrict__ QKV, unsigned short* __restrict__ Ctx,
    int nqt, int qoff, int orows)
{
  __shared__ short Ks[64*72];      // [key][hd], 144B row stride
  __shared__ short Vt[64*72];      // [hd][key] transposed, slot-XOR swizzled
  __shared__ short Ps[4*16*72];    // per-wave P tile [q][key]
  int bid = blockIdx.x;
  const int nwg = gridDim.x;                 // always % 8 == 0 (2304 or 256)
  bid = (bid & 7) * (nwg >> 3) + (bid >> 3);
  const int qt = bid % nqt;
  const int h  = (bid / nqt) % H_;
  const int bb = bid / (nqt*H_);
  const int tid = threadIdx.x;
  const int w = tid >> 6, lane = tid & 63, l15 = lane & 15, l4 = lane >> 4;

  const size_t rowQ = (size_t)bb*S_ + qoff + (size_t)qt*64 + w*16 + l15;
  const unsigned short* qp = QKV + rowQ*1536 + h*64;
  const bf16x8 qf0 = *(const bf16x8*)(qp + l4*8);
  const bf16x8 qf1 = *(const bf16x8*)(qp + 32 + l4*8);

  const unsigned short* Kg = QKV + (size_t)bb*S_*1536 + 512 + h*64;
  const unsigned short* Vg = Kg + 512;

  f32x4 ctx[4] = {};
  f32x4 lacc = {};                 // row-sum accumulator (all cols identical)

  const bf16x8 onesv = {(short)0x3F80,(short)0x3F80,(short)0x3F80,(short)0x3F80,
                        (short)0x3F80,(short)0x3F80,(short)0x3F80,(short)0x3F80};

  char* PsW = (char*)Ps + w*2304;

  const int skey = tid >> 3, shc = tid & 7;
  const int vp   = tid >> 3, vhc = tid & 7;

  const unsigned short* gK = Kg + (size_t)skey*1536 + shc*8;
  const unsigned short* gV = Vg + (size_t)(2*vp)*1536 + vhc*8;
  bf16x8 k0v = *(const bf16x8*)gK;
  bf16x8 k1v = *(const bf16x8*)(gK + 32*1536);
  bf16x8 c0  = *(const bf16x8*)gV;
  bf16x8 c1  = *(const bf16x8*)(gV + 1536);

  for (int kt = 0; kt < 16; kt++) {
    __syncthreads();
    *(bf16x8*)((char*)Ks + skey*144      + shc*16) = k0v;
    *(bf16x8*)((char*)Ks + (skey+32)*144 + shc*16) = k1v;
    #pragma unroll
    for (int j = 0; j < 8; j++) {
      const int hd = vhc*8 + j;
      unsigned int val = (unsigned int)(unsigned short)c0[j]
                       | ((unsigned int)(unsigned short)c1[j] << 16);
      *(unsigned int*)((char*)Vt + hd*144 + ((4*vp) ^ (vhc<<4))) = val;
    }
    __syncthreads();
    // T14: issue next tile's global loads now; latency hides under compute
    if (kt < 15) {
      const unsigned short* nK = gK + (size_t)(kt+1)*98304;
      const unsigned short* nV = gV + (size_t)(kt+1)*98304;
      k0v = *(const bf16x8*)nK;
      k1v = *(const bf16x8*)(nK + 32*1536);
      c0  = *(const bf16x8*)nV;
      c1  = *(const bf16x8*)(nV + 1536);
    }

    // S = Q K^T  (log2-domain scores; Q pre-scaled)
    f32x4 sac[4] = {};
    __builtin_amdgcn_s_setprio(1);
    #pragma unroll
    for (int nf = 0; nf < 4; nf++) {
      const char* kb = (char*)Ks + (nf*16 + l15)*144 + l4*16;
      bf16x8 b0 = *(const bf16x8*)kb;
      bf16x8 b1 = *(const bf16x8*)(kb + 64);
      sac[nf] = MFMA16(qf0, b0, sac[nf]);
      sac[nf] = MFMA16(qf1, b1, sac[nf]);
    }
    __builtin_amdgcn_s_setprio(0);

    // P = exp2(s) -> LDS truncated bf16 (no max subtraction needed)
    #pragma unroll
    for (int r = 0; r < 4; r++) {
      unsigned short* pw = (unsigned short*)(PsW + (l4*4 + r)*144);
      pw[ 0 + l15] = (unsigned short)(__float_as_uint(__builtin_amdgcn_exp2f(sac[0][r])) >> 16);
      pw[16 + l15] = (unsigned short)(__float_as_uint(__builtin_amdgcn_exp2f(sac[1][r])) >> 16);
      pw[32 + l15] = (unsigned short)(__float_as_uint(__builtin_amdgcn_exp2f(sac[2][r])) >> 16);
      pw[48 + l15] = (unsigned short)(__float_as_uint(__builtin_amdgcn_exp2f(sac[3][r])) >> 16);
    }

    // PV: ctx += P(16xkeys) * V(keys x 64hd); l += P * ones
    const char* pb = PsW + l15*144 + l4*16;
    const bf16x8 pf0 = *(const bf16x8*)pb;
    const bf16x8 pf1 = *(const bf16x8*)(pb + 64);
    __builtin_amdgcn_s_setprio(1);
    lacc = MFMA16(pf0, onesv, lacc);
    lacc = MFMA16(pf1, onesv, lacc);
    #pragma unroll
    for (int hf = 0; hf < 4; hf++) {
      const int hd = hf*16 + l15;
      const int hc = (hd >> 3) & 7;
      const char* vb = (char*)Vt + hd*144;
      bf16x8 v0 = *(const bf16x8*)(vb + ((l4*16)     ^ (hc<<4)));
      bf16x8 v1 = *(const bf16x8*)(vb + (((l4+4)*16) ^ (hc<<4)));
      ctx[hf] = MFMA16(pf0, v0, ctx[hf]);
      ctx[hf] = MFMA16(pf1, v1, ctx[hf]);
    }
    __builtin_amdgcn_s_setprio(0);
  }

  // epilogue: divide by l, store bf16 ctx
  #pragma unroll
  for (int r = 0; r < 4; r++) {
    const float invl = 1.0f / lacc[r];
    const size_t row = (size_t)bb*orows + (size_t)qt*64 + w*16 + l4*4 + r;
    unsigned short* op = Ctx + row*512 + h*64;
    op[ 0 + l15] = f2b(ctx[0][r]*invl);
    op[16 + l15] = f2b(ctx[1][r]*invl);
    op[32 + l15] = f2b(ctx[2][r]*invl);
    op[48 + l15] = f2b(ctx[3][r]*invl);
  }
}

// ---------------- row LayerNorm over D=512: fp32 in, bf16 out ----------------------
__global__ __launch_bounds__(256) void ln_kernel(
    const float* __restrict__ Yin, const float* __restrict__ g, const float* __restrict__ b,
    unsigned short* __restrict__ Xb)
{
  int row = blockIdx.x, tid = threadIdx.x;
  const float* yr = Yin + (size_t)row*D_;
  float v0 = yr[tid], v1 = yr[tid + 256];
  __shared__ float red[4];
  float s = waveSum(v0 + v1);
  if ((tid & 63) == 0) red[tid >> 6] = s;
  __syncthreads();
  float mu = (red[0] + red[1] + red[2] + red[3]) * (1.f/512.f);
  __syncthreads();
  float d0 = v0 - mu, d1 = v1 - mu;
  float ss = waveSum(d0*d0 + d1*d1);
  if ((tid & 63) == 0) red[tid >> 6] = ss;
  __syncthreads();
  float inv = rsqrtf((red[0] + red[1] + red[2] + red[3]) * (1.f/512.f) + 1e-5f);
  Xb[(size_t)row*D_ + tid]       = f2b(d0 * inv * g[tid]       + b[tid]);
  Xb[(size_t)row*D_ + tid + 256] = f2b(d1 * inv * g[tid + 256] + b[tid + 256]);
}

// ---------------- head: Xq[row](bf16) @ W_head[512,32] + b_head --------------------
__global__ __launch_bounds__(64) void head_kernel(
    const unsigned short* __restrict__ Xq, const float* __restrict__ W_head,
    const float* __restrict__ b_head, float* __restrict__ out)
{
  int row = blockIdx.x;            // 0..MQ_-1
  const unsigned short* xr = Xq + (size_t)row*D_;
  __shared__ float xs[512];
  int tid = threadIdx.x;
  for (int i = tid; i < 512; i += 64) xs[i] = b2f(xr[i]);
  __syncthreads();
  if (tid < 32) {
    float acc = b_head[tid];
    #pragma unroll 8
    for (int k = 0; k < 512; k++) acc += xs[k] * W_head[k*32 + tid];
    out[(size_t)row*32 + tid] = acc;
  }
}

extern "C" void kernel_launch(void* const* d_in, const int* in_sizes, int n_in,
                              void* d_out, int out_size, void* d_ws, size_t ws_size,
                              hipStream_t stream)
{
  const float* x_c      = (const float*)d_in[0];
  const float* y_c      = (const float*)d_in[1];
  const float* x_q      = (const float*)d_in[2];
  const float* W_val    = (const float*)d_in[3];
  const float* b_val    = (const float*)d_in[4];
  const float* q_emb    = (const float*)d_in[5];
  const float* in_proj_w= (const float*)d_in[6];
  const float* in_proj_b= (const float*)d_in[7];
  const float* out_w    = (const float*)d_in[8];
  const float* out_b    = (const float*)d_in[9];
  const float* ln1_g    = (const float*)d_in[10];
  const float* ln1_b    = (const float*)d_in[11];
  const float* lin1_w   = (const float*)d_in[12];
  const float* lin1_b   = (const float*)d_in[13];
  const float* lin2_w   = (const float*)d_in[14];
  const float* lin2_b   = (const float*)d_in[15];
  const float* ln2_g    = (const float*)d_in[16];
  const float* ln2_b    = (const float*)d_in[17];
  const float* W_head   = (const float*)d_in[18];
  const float* b_head   = (const float*)d_in[19];
  float* out = (float*)d_out;

  // workspace layout (~250 MB); residual stream is bf16 (Xb1/Xb2), Yf = pre-LN fp32
  char* p = (char*)d_ws;
  float* Yf = (float*)p;                     p += (size_t)M_*D_*4;    // GEMM+res out
  unsigned short* hid  = (unsigned short*)p; p += (size_t)M_*HID_*2;
  unsigned short* Xb2  = (unsigned short*)p; p += (size_t)M_*D_*2;    // ln2/embed out
  unsigned short* qkv  = (unsigned short*)p; p += (size_t)M_*3*D_*2;
  unsigned short* Xb1  = qkv;                                          // alias: ln1 out (disjoint live range)
  unsigned short* ctxb = (unsigned short*)p; p += (size_t)M_*D_*2;
  unsigned short* ipwB = (unsigned short*)p; p += (size_t)L_*3*D_*D_*2;
  unsigned short* owB  = (unsigned short*)p; p += (size_t)L_*D_*D_*2;
  unsigned short* w1B  = (unsigned short*)p; p += (size_t)L_*HID_*D_*2;
  unsigned short* w2B  = (unsigned short*)p; p += (size_t)L_*D_*HID_*2;
  unsigned short* XYb  = (unsigned short*)p; p += (size_t)M_*128*2;
  unsigned short* Wemb = (unsigned short*)p; p += (size_t)D_*128*2;
  float* zbias         = (float*)p;          p += 2048*4;
  float* qkvbias       = (float*)p;          p += L_*1536*4;

  // compact layer-6 buffers (alias XYb region, idle post-embed)
  unsigned short* ctxq  = ctxb;                                   // [MQ_,512]
  float*          Yfq   = Yf;                                     // [MQ_,512] fp32
  unsigned short* hidq  = hid;                                    // [MQ_,2048]
  unsigned short* Xqb2  = XYb;                                    // gathered residual
  unsigned short* Xqb1  = XYb + (size_t)MQ_*D_;                   // ln1 out

  (void)hipMemsetAsync(zbias, 0, 2048*4, stream);

  // convert weights to bf16 (Q rows of in_proj pre-scaled by 0.125*log2e)
  f2bq_kernel<<<512, 256, 0, stream>>>(in_proj_w, ipwB, L_*3*D_*D_/4);
  sbias_kernel<<<36, 256, 0, stream>>>(in_proj_b, qkvbias);
  f2b_kernel<<<512, 256, 0, stream>>>(out_w,     owB,  L_*D_*D_/4);
  f2b_kernel<<<512, 256, 0, stream>>>(lin1_w,    w1B,  L_*HID_*D_/4);
  f2b_kernel<<<512, 256, 0, stream>>>(lin2_w,    w2B,  L_*D_*HID_/4);
  wemb_kernel<<<256, 256, 0, stream>>>(W_val, b_val, q_emb, Wemb);
  packxy_kernel<<<1024, 256, 0, stream>>>(x_c, y_c, x_q, XYb);

  // embedding as GEMM (bf16 out -> Xb2)
  bgemm_kernel<0,1><<<dim3(4, 144), 256, 0, stream>>>(
      XYb, Wemb, zbias, nullptr, Xb2, D_, 128);

  for (int l = 0; l < L_ - 1; l++) {
    // QKV projection (bf16 out, scaled Q)
    bgemm_kernel<0,1><<<dim3(12, 144), 256, 0, stream>>>(
        Xb2, ipwB + (size_t)l*3*D_*D_, qkvbias + (size_t)l*3*D_,
        nullptr, qkv, 3*D_, D_);
    // attention (full: 18 q-tiles per (b,h))
    mattn_kernel<<<B_*H_*18, 256, 0, stream>>>(qkv, ctxb, 18, 0, S_);
    // out-proj + bf16 residual(Xb2) -> Yf fp32  (BK=64)
    bgemm64_kernel<<<dim3(8, 144), 256, 0, stream>>>(
        ctxb, owB + (size_t)l*D_*D_, out_b + (size_t)l*D_, Xb2, Yf, D_, D_);
    ln_kernel<<<M_, 256, 0, stream>>>(Yf, ln1_g + (size_t)l*D_, ln1_b + (size_t)l*D_, Xb1);
    // FFN1 (relu, bf16 out)
    bgemm_kernel<1,1><<<dim3(16, 144), 256, 0, stream>>>(
        Xb1, w1B + (size_t)l*HID_*D_, lin1_b + (size_t)l*HID_,
        nullptr, hid, HID_, D_);
    // FFN2 + bf16 residual(Xb1) -> Yf  (BK=64)
    bgemm64_kernel<<<dim3(8, 144), 256, 0, stream>>>(
        hid, w2B + (size_t)l*D_*HID_, lin2_b + (size_t)l*D_, Xb1, Yf, D_, HID_);
    ln_kernel<<<M_, 256, 0, stream>>>(Yf, ln2_g + (size_t)l*D_, ln2_b + (size_t)l*D_, Xb2);
  }

  // ---------- layer 6 (l = L_-1): only query rows reach the head ----------
  {
    const int l = L_ - 1;
    bgemm_kernel<0,1><<<dim3(12, 144), 256, 0, stream>>>(
        Xb2, ipwB + (size_t)l*3*D_*D_, qkvbias + (size_t)l*3*D_,
        nullptr, qkv, 3*D_, D_);
    // attention only for the 2 query q-tiles per (b,h); compact output [MQ_,512]
    mattn_kernel<<<B_*H_*2, 256, 0, stream>>>(qkv, ctxq, 2, C_, Q_);
    // gather query rows of Xb2 -> Xqb2 (bf16)
    gatherq_kernel<<<MQ_, 256, 0, stream>>>(Xb2, Xqb2);
    // out-proj + residual(Xqb2) -> Yfq (M = 2048)
    bgemm64_kernel<<<dim3(8, 16), 256, 0, stream>>>(
        ctxq, owB + (size_t)l*D_*D_, out_b + (size_t)l*D_, Xqb2, Yfq, D_, D_);
    ln_kernel<<<MQ_, 256, 0, stream>>>(Yfq, ln1_g + (size_t)l*D_, ln1_b + (size_t)l*D_, Xqb1);
    // FFN1 (relu) compact
    bgemm_kernel<1,1><<<dim3(16, 16), 256, 0, stream>>>(
        Xqb1, w1B + (size_t)l*HID_*D_, lin1_b + (size_t)l*HID_,
        nullptr, hidq, HID_, D_);
    // FFN2 + residual(Xqb1) -> Yfq
    bgemm64_kernel<<<dim3(8, 16), 256, 0, stream>>>(
        hidq, w2B + (size_t)l*D_*HID_, lin2_b + (size_t)l*D_, Xqb1, Yfq, D_, HID_);
    // final LN2 -> reuse Xqb2 slot (dead after out-proj)
    ln_kernel<<<MQ_, 256, 0, stream>>>(Yfq, ln2_g + (size_t)l*D_, ln2_b + (size_t)l*D_, Xqb2);
  }

  head_kernel<<<MQ_, 64, 0, stream>>>(Xqb2, W_head, b_head, out);
}

// Round 17
// 1580.548 us; speedup vs baseline: 1.1448x; 1.0027x over previous
//
#include <hip/hip_runtime.h>

#define B_   16
#define C_   1024
#define Q_   128
#define S_   1152
#define D_   512
#define H_   8
#define HID_ 2048
#define L_   6
#define M_   (B_*S_)   // 18432 tokens
#define MQ_  (B_*Q_)   // 2048 query tokens
#define QSC_ 0.18033688011f   // 0.125 * log2(e): folds 1/sqrt(64) and 1/ln2 into Q

typedef short bf16x8 __attribute__((ext_vector_type(8)));
typedef float f32x4  __attribute__((ext_vector_type(4)));
#define MFMA16(a,b,c) __builtin_amdgcn_mfma_f32_16x16x32_bf16(a,b,c,0,0,0)

__device__ __forceinline__ unsigned short f2b(float f){
  union { float f; unsigned u; } v; v.f = f;
  return (unsigned short)((v.u + 0x7FFF + ((v.u >> 16) & 1)) >> 16);  // RNE
}
__device__ __forceinline__ float b2f(unsigned short u){
  return __uint_as_float((unsigned)u << 16);
}
__device__ __forceinline__ void gload16(const void* g, void* l){
  __builtin_amdgcn_global_load_lds((const __attribute__((address_space(1))) void*)g,
                                   (__attribute__((address_space(3))) void*)l, 16, 0, 0);
}
__device__ __forceinline__ float waveSum(float v){
  #pragma unroll
  for (int o = 32; o > 0; o >>= 1) v += __shfl_down(v, o, 64);
  return v;
}

// ---------------- fp32 -> bf16 weight conversion ----------------------------------
__global__ __launch_bounds__(256) void f2b_kernel(
    const float* __restrict__ in, unsigned short* __restrict__ out, int n4)
{
  int i = blockIdx.x*256 + threadIdx.x;
  for (; i < n4; i += gridDim.x*256) {
    float4 v = ((const float4*)in)[i];
    ushort4 o = { f2b(v.x), f2b(v.y), f2b(v.z), f2b(v.w) };
    ((ushort4*)out)[i] = o;
  }
}

// ---------------- in_proj_w -> bf16 with Q-rows pre-scaled by QSC_ -----------------
__global__ __launch_bounds__(256) void f2bq_kernel(
    const float* __restrict__ in, unsigned short* __restrict__ out, int n4)
{
  int i = blockIdx.x*256 + threadIdx.x;
  for (; i < n4; i += gridDim.x*256) {
    const int row = (i >> 7) % 1536;          // 128 float4 per 512-col row
    const float s = (row < 512) ? QSC_ : 1.f;
    float4 v = ((const float4*)in)[i];
    ushort4 o = { f2b(v.x*s), f2b(v.y*s), f2b(v.z*s), f2b(v.w*s) };
    ((ushort4*)out)[i] = o;
  }
}

// ---------------- in_proj_b scaled copy (Q part * QSC_) ----------------------------
__global__ __launch_bounds__(256) void sbias_kernel(
    const float* __restrict__ in, float* __restrict__ out)
{
  int idx = blockIdx.x*256 + threadIdx.x;     // L_*1536 = 9216
  if (idx < L_*1536) {
    int j = idx % 1536;
    out[idx] = in[idx] * (j < 512 ? QSC_ : 1.f);
  }
}

// ---------------- pack XY [M,128] bf16: x | y/0 | 1 | isq | zeros ------------------
__global__ __launch_bounds__(256) void packxy_kernel(
    const float* __restrict__ x_c, const float* __restrict__ y_c,
    const float* __restrict__ x_q, unsigned short* __restrict__ XY)
{
  int idx = blockIdx.x*256 + threadIdx.x;
  const int n = M_*128;
  for (; idx < n; idx += gridDim.x*256) {
    int row = idx >> 7, col = idx & 127;
    int bb = row / S_, s = row % S_;
    float v;
    if (col < 64) {
      v = (s < C_) ? x_c[((size_t)bb*C_ + s)*64 + col]
                   : x_q[((size_t)bb*Q_ + (s - C_))*64 + col];
    } else if (col < 96) {
      v = (s < C_) ? y_c[((size_t)bb*C_ + s)*32 + (col - 64)] : 0.f;
    } else if (col == 96) {
      v = 1.f;
    } else if (col == 97) {
      v = (s >= C_) ? 1.f : 0.f;
    } else v = 0.f;
    XY[idx] = f2b(v);
  }
}

// ---------------- build Wemb [512][128] bf16 (W_val^T | b_val | q_emb | 0) ---------
__global__ __launch_bounds__(256) void wemb_kernel(
    const float* __restrict__ W_val, const float* __restrict__ b_val,
    const float* __restrict__ q_emb, unsigned short* __restrict__ Wemb)
{
  int idx = blockIdx.x*256 + threadIdx.x;   // 512*128 = 65536 = 256*256
  int nn = idx >> 7, k = idx & 127;
  float v;
  if (k < 96)       v = W_val[k*D_ + nn];
  else if (k == 96) v = b_val[nn];
  else if (k == 97) v = q_emb[nn];
  else              v = 0.f;
  Wemb[idx] = f2b(v);
}

// ---------------- gather query rows (bf16) -> compact [MQ_,512] --------------------
__global__ __launch_bounds__(256) void gatherq_kernel(
    const unsigned short* __restrict__ X, unsigned short* __restrict__ Xq)
{
  int row = blockIdx.x;                 // 0..MQ_-1
  int bb = row >> 7, qi = row & 127;
  const unsigned short* src = X + ((size_t)bb*S_ + C_ + qi)*D_;
  unsigned short* dst = Xq + (size_t)row*D_;
  int tid = threadIdx.x;
  dst[tid] = src[tid];
  dst[tid + 256] = src[tid + 256];
}

// T2 swizzle (BK=32 kernels): LDS slot (row, c in 0..3) holds global chunk c ^ SWZ(row)
#define SWZ(row) (((row) >> 1) & 3)
// T2 swizzle (BK=64 kernel): 8 chunks of 16B per 128B row; slot c holds chunk c ^ (row&7)

// ---------------- bf16 MFMA GEMM, 2-phase double-buffered, 128x128 tile, BK=32 -----
// BOUT: 0 = f32 out, 1 = bf16 out.
template<int RELU, int BOUT>
__global__ __launch_bounds__(256) void bgemm_kernel(
    const unsigned short* __restrict__ A, const unsigned short* __restrict__ W,
    const float* __restrict__ bias,
    float* __restrict__ Cf, unsigned short* __restrict__ Cb, int Nn, int Kk)
{
  __shared__ short As[2][4096];     // [buf][128][32] bf16
  __shared__ short Bs[2][4096];
  int lin = blockIdx.y * gridDim.x + blockIdx.x;
  const int nwg = gridDim.x * gridDim.y;
  const int cpx = nwg >> 3;
  lin = (lin & 7) * cpx + (lin >> 3);
  const int bm = (lin / gridDim.x) * 128, bn = (lin % gridDim.x) * 128;

  const int tid = threadIdx.x;
  const int w = tid >> 6, lane = tid & 63, l15 = lane & 15, l4 = lane >> 4;
  const int wm = w >> 1, wn = w & 1;
  f32x4 acc[4][4] = {};
  const size_t strA = (size_t)Kk * 2;          // bytes per row
  const char* Abase = (const char*)A + (size_t)bm * strA;
  const char* Wbase = (const char*)W + (size_t)bn * strA;
  const int srow = tid >> 2;
  const int schunk = (tid & 3) ^ SWZ(srow);    // pre-swizzled source chunk
  const size_t soff = (size_t)srow * strA + (size_t)(schunk * 16);
  const int ldsOff = w * 1024;

#define STAGEK(K0, BUF) do { \
    const char* a0_ = Abase + soff + (size_t)(K0)*2; \
    const char* b0_ = Wbase + soff + (size_t)(K0)*2; \
    char* la_ = (char*)As + (BUF)*8192 + ldsOff; \
    char* lb_ = (char*)Bs + (BUF)*8192 + ldsOff; \
    gload16(a0_,            la_); \
    gload16(a0_ + 64*strA,  la_ + 4096); \
    gload16(b0_,            lb_); \
    gload16(b0_ + 64*strA,  lb_ + 4096); \
  } while(0)

  STAGEK(0, 0);
  const int nk = Kk >> 5;
  for (int t = 0; t < nk; t++) {
    __syncthreads();                       // buf[t&1] staged; prior reads done
    if (t + 1 < nk) STAGEK((t+1)*32, (t+1)&1);   // prefetch under this tile's MFMAs
    const short* AsC = (const short*)As + (t&1)*4096;
    const short* BsC = (const short*)Bs + (t&1)*4096;
    bf16x8 af[4], bfr[4];
    #pragma unroll
    for (int mf = 0; mf < 4; mf++) {
      const int ar = wm*64 + mf*16 + l15;
      af[mf] = *(const bf16x8*)(AsC + ar*32 + (l4 ^ SWZ(ar))*8);
    }
    #pragma unroll
    for (int nf = 0; nf < 4; nf++) {
      const int br = wn*64 + nf*16 + l15;
      bfr[nf] = *(const bf16x8*)(BsC + br*32 + (l4 ^ SWZ(br))*8);
    }
    #pragma unroll
    for (int mf = 0; mf < 4; mf++)
      #pragma unroll
      for (int nf = 0; nf < 4; nf++)
        acc[mf][nf] = MFMA16(af[mf], bfr[nf], acc[mf][nf]);
  }
#undef STAGEK

  #pragma unroll
  for (int mf = 0; mf < 4; mf++) {
    #pragma unroll
    for (int nf = 0; nf < 4; nf++) {
      const int ccol = bn + wn*64 + nf*16 + l15;
      const float bv = bias[ccol];
      #pragma unroll
      for (int r = 0; r < 4; r++) {
        const int rrow = bm + wm*64 + mf*16 + l4*4 + r;
        float o = acc[mf][nf][r] + bv;
        if (RELU) o = fmaxf(o, 0.f);
        if (BOUT == 1) Cb[(size_t)rrow*Nn + ccol] = f2b(o);
        else           Cf[(size_t)rrow*Nn + ccol] = o;
      }
    }
  }
}

// ---------------- bf16 MFMA GEMM, 128x64 tile, BK=64, 2-phase dbuf -----------------
// bf16 residual, bf16 out (pre-LN stream). 16 MFMA / 12 ds_read per iter.
__global__ __launch_bounds__(256) void bgemm64_kernel(
    const unsigned short* __restrict__ A, const unsigned short* __restrict__ W,
    const float* __restrict__ bias, const unsigned short* __restrict__ Rsd,
    unsigned short* __restrict__ Cb, int Nn, int Kk)
{
  __shared__ short As[2][8192];     // [buf][128][64] bf16
  __shared__ short Bs[2][4096];     // [buf][64][64]  bf16
  int lin = blockIdx.y * gridDim.x + blockIdx.x;
  const int nwg = gridDim.x * gridDim.y;
  const int cpx = nwg >> 3;
  lin = (lin & 7) * cpx + (lin >> 3);
  const int bm = (lin / gridDim.x) * 128, bn = (lin % gridDim.x) * 64;

  const int tid = threadIdx.x;
  const int w = tid >> 6, lane = tid & 63, l15 = lane & 15, l4 = lane >> 4;
  f32x4 acc[2][4] = {};
  const size_t strA = (size_t)Kk * 2;
  const char* Abase = (const char*)A + (size_t)bm * strA;
  const char* Wbase = (const char*)W + (size_t)bn * strA;
  const int srow = tid >> 3;                   // 0..31 (32 rows per 4KB stage call)
  const int schunk = (tid & 7) ^ (srow & 7);   // pre-swizzled source chunk (16B)
  const size_t soff = (size_t)srow * strA + (size_t)(schunk * 16);
  const int ldsOff = w * 1024;

#define STG64(K0, BUF) do { \
    const char* a0_ = Abase + soff + (size_t)(K0)*2; \
    const char* b0_ = Wbase + soff + (size_t)(K0)*2; \
    char* la_ = (char*)As + (BUF)*16384 + ldsOff; \
    char* lb_ = (char*)Bs + (BUF)*8192  + ldsOff; \
    gload16(a0_,            la_); \
    gload16(a0_ + 32*strA,  la_ + 4096); \
    gload16(a0_ + 64*strA,  la_ + 8192); \
    gload16(a0_ + 96*strA,  la_ + 12288); \
    gload16(b0_,            lb_); \
    gload16(b0_ + 32*strA,  lb_ + 4096); \
  } while(0)

  STG64(0, 0);
  const int nk = Kk >> 6;
  for (int t = 0; t < nk; t++) {
    __syncthreads();                       // buf[t&1] staged; prior reads done
    if (t + 1 < nk) STG64((t+1)*64, (t+1)&1);
    const short* AsC = (const short*)As + (t&1)*8192;
    const short* BsC = (const short*)Bs + (t&1)*4096;
    bf16x8 af[2][2], bfr[4][2];
    #pragma unroll
    for (int mf = 0; mf < 2; mf++) {
      const int ar = w*32 + mf*16 + l15;
      #pragma unroll
      for (int ks = 0; ks < 2; ks++) {
        const int c = ks*4 + l4;
        af[mf][ks] = *(const bf16x8*)(AsC + ar*64 + (c ^ (ar & 7))*8);
      }
    }
    #pragma unroll
    for (int nf = 0; nf < 4; nf++) {
      const int br = nf*16 + l15;
      #pragma unroll
      for (int ks = 0; ks < 2; ks++) {
        const int c = ks*4 + l4;
        bfr[nf][ks] = *(const bf16x8*)(BsC + br*64 + (c ^ (br & 7))*8);
      }
    }
    #pragma unroll
    for (int ks = 0; ks < 2; ks++)
      #pragma unroll
      for (int mf = 0; mf < 2; mf++)
        #pragma unroll
        for (int nf = 0; nf < 4; nf++)
          acc[mf][nf] = MFMA16(af[mf][ks], bfr[nf][ks], acc[mf][nf]);
  }
#undef STG64

  #pragma unroll
  for (int mf = 0; mf < 2; mf++) {
    #pragma unroll
    for (int nf = 0; nf < 4; nf++) {
      const int ccol = bn + nf*16 + l15;
      const float bv = bias[ccol];
      #pragma unroll
      for (int r = 0; r < 4; r++) {
        const int rrow = bm + w*32 + mf*16 + l4*4 + r;
        float o = acc[mf][nf][r] + bv + b2f(Rsd[(size_t)rrow*Nn + ccol]);
        Cb[(size_t)rrow*Nn + ccol] = f2b(o);
      }
    }
  }
}

// ---------------- MFMA flash attention, QBLK=128, base-2 softmax, no running max ---
// block = (b,h,128-q-tile); 4 waves x 32 q-rows (2 groups of 16). K-tiles of 64.
__global__ __launch_bounds__(256) void mattn_kernel(
    const unsigned short* __restrict__ QKV, unsigned short* __restrict__ Ctx,
    int nqt, int qoff, int orows)
{
  __shared__ short Ks[64*72];       // [key][hd], 144B row stride
  __shared__ short Vt[64*72];       // [hd][key] transposed, slot-XOR swizzled
  __shared__ short Ps[4*32*72];     // per-wave P tile [32 q][64 key]
  int bid = blockIdx.x;
  const int nwg = gridDim.x;                 // always % 8 == 0 (1152 or 128)
  bid = (bid & 7) * (nwg >> 3) + (bid >> 3);
  const int qt = bid % nqt;
  const int h  = (bid / nqt) % H_;
  const int bb = bid / (nqt*H_);
  const int tid = threadIdx.x;
  const int w = tid >> 6, lane = tid & 63, l15 = lane & 15, l4 = lane >> 4;

  bf16x8 qA[2][2];
  #pragma unroll
  for (int g = 0; g < 2; g++) {
    const size_t rowQ = (size_t)bb*S_ + qoff + (size_t)qt*128 + w*32 + g*16 + l15;
    const unsigned short* qp = QKV + rowQ*1536 + h*64;
    qA[g][0] = *(const bf16x8*)(qp + l4*8);
    qA[g][1] = *(const bf16x8*)(qp + 32 + l4*8);
  }

  const unsigned short* Kg = QKV + (size_t)bb*S_*1536 + 512 + h*64;
  const unsigned short* Vg = Kg + 512;

  f32x4 ctx[2][4] = {};
  f32x4 lacc[2] = {};

  const bf16x8 onesv = {(short)0x3F80,(short)0x3F80,(short)0x3F80,(short)0x3F80,
                        (short)0x3F80,(short)0x3F80,(short)0x3F80,(short)0x3F80};

  char* PsW = (char*)Ps + w*4608;            // 32*144 bytes per wave

  const int skey = tid >> 3, shc = tid & 7;
  const int vp   = tid >> 3, vhc = tid & 7;

  const unsigned short* gK = Kg + (size_t)skey*1536 + shc*8;
  const unsigned short* gV = Vg + (size_t)(2*vp)*1536 + vhc*8;
  bf16x8 k0v = *(const bf16x8*)gK;
  bf16x8 k1v = *(const bf16x8*)(gK + 32*1536);
  bf16x8 c0  = *(const bf16x8*)gV;
  bf16x8 c1  = *(const bf16x8*)(gV + 1536);

  for (int kt = 0; kt < 16; kt++) {
    __syncthreads();
    *(bf16x8*)((char*)Ks + skey*144      + shc*16) = k0v;
    *(bf16x8*)((char*)Ks + (skey+32)*144 + shc*16) = k1v;
    #pragma unroll
    for (int j = 0; j < 8; j++) {
      const int hd = vhc*8 + j;
      unsigned int val = (unsigned int)(unsigned short)c0[j]
                       | ((unsigned int)(unsigned short)c1[j] << 16);
      *(unsigned int*)((char*)Vt + hd*144 + ((4*vp) ^ (vhc<<4))) = val;
    }
    __syncthreads();
    // T14: issue next tile's global loads now; latency hides under compute
    if (kt < 15) {
      const unsigned short* nK = gK + (size_t)(kt+1)*98304;
      const unsigned short* nV = gV + (size_t)(kt+1)*98304;
      k0v = *(const bf16x8*)nK;
      k1v = *(const bf16x8*)(nK + 32*1536);
      c0  = *(const bf16x8*)nV;
      c1  = *(const bf16x8*)(nV + 1536);
    }

    // S = Q K^T  (log2-domain scores; Q pre-scaled): 32 q-rows x 64 keys per wave
    f32x4 sac[2][4] = {};
    __builtin_amdgcn_s_setprio(1);
    #pragma unroll
    for (int nf = 0; nf < 4; nf++) {
      const char* kb = (char*)Ks + (nf*16 + l15)*144 + l4*16;
      bf16x8 b0 = *(const bf16x8*)kb;
      bf16x8 b1 = *(const bf16x8*)(kb + 64);
      #pragma unroll
      for (int g = 0; g < 2; g++) {
        sac[g][nf] = MFMA16(qA[g][0], b0, sac[g][nf]);
        sac[g][nf] = MFMA16(qA[g][1], b1, sac[g][nf]);
      }
    }
    __builtin_amdgcn_s_setprio(0);

    // P = exp2(s) -> LDS truncated bf16 (no max subtraction)
    #pragma unroll
    for (int g = 0; g < 2; g++)
      #pragma unroll
      for (int r = 0; r < 4; r++) {
        unsigned short* pw = (unsigned short*)(PsW + (g*16 + l4*4 + r)*144);
        pw[ 0 + l15] = (unsigned short)(__float_as_uint(__builtin_amdgcn_exp2f(sac[g][0][r])) >> 16);
        pw[16 + l15] = (unsigned short)(__float_as_uint(__builtin_amdgcn_exp2f(sac[g][1][r])) >> 16);
        pw[32 + l15] = (unsigned short)(__float_as_uint(__builtin_amdgcn_exp2f(sac[g][2][r])) >> 16);
        pw[48 + l15] = (unsigned short)(__float_as_uint(__builtin_amdgcn_exp2f(sac[g][3][r])) >> 16);
      }

    // PV: ctx += P(32q x 64k) * V(64k x 64hd); l += P * ones
    bf16x8 pf[2][2];
    #pragma unroll
    for (int g = 0; g < 2; g++) {
      const char* pb = PsW + (g*16 + l15)*144 + l4*16;
      pf[g][0] = *(const bf16x8*)pb;
      pf[g][1] = *(const bf16x8*)(pb + 64);
    }
    __builtin_amdgcn_s_setprio(1);
    #pragma unroll
    for (int g = 0; g < 2; g++) {
      lacc[g] = MFMA16(pf[g][0], onesv, lacc[g]);
      lacc[g] = MFMA16(pf[g][1], onesv, lacc[g]);
    }
    #pragma unroll
    for (int hf = 0; hf < 4; hf++) {
      const int hd = hf*16 + l15;
      const int hc = (hd >> 3) & 7;
      const char* vb = (char*)Vt + hd*144;
      bf16x8 v0 = *(const bf16x8*)(vb + ((l4*16)     ^ (hc<<4)));
      bf16x8 v1 = *(const bf16x8*)(vb + (((l4+4)*16) ^ (hc<<4)));
      #pragma unroll
      for (int g = 0; g < 2; g++) {
        ctx[g][hf] = MFMA16(pf[g][0], v0, ctx[g][hf]);
        ctx[g][hf] = MFMA16(pf[g][1], v1, ctx[g][hf]);
      }
    }
    __builtin_amdgcn_s_setprio(0);
  }

  // epilogue: divide by l, store bf16 ctx
  #pragma unroll
  for (int g = 0; g < 2; g++)
    #pragma unroll
    for (int r = 0; r < 4; r++) {
      const float invl = 1.0f / lacc[g][r];
      const size_t row = (size_t)bb*orows + (size_t)qt*128 + w*32 + g*16 + l4*4 + r;
      unsigned short* op = Ctx + row*512 + h*64;
      op[ 0 + l15] = f2b(ctx[g][0][r]*invl);
      op[16 + l15] = f2b(ctx[g][1][r]*invl);
      op[32 + l15] = f2b(ctx[g][2][r]*invl);
      op[48 + l15] = f2b(ctx[g][3][r]*invl);
    }
}

// ---------------- row LayerNorm over D=512: bf16 in, bf16 out ----------------------
__global__ __launch_bounds__(256) void ln_kernel(
    const unsigned short* __restrict__ Yin, const float* __restrict__ g, const float* __restrict__ b,
    unsigned short* __restrict__ Xb)
{
  int row = blockIdx.x, tid = threadIdx.x;
  const unsigned short* yr = Yin + (size_t)row*D_;
  float v0 = b2f(yr[tid]), v1 = b2f(yr[tid + 256]);
  __shared__ float red[4];
  float s = waveSum(v0 + v1);
  if ((tid & 63) == 0) red[tid >> 6] = s;
  __syncthreads();
  float mu = (red[0] + red[1] + red[2] + red[3]) * (1.f/512.f);
  __syncthreads();
  float d0 = v0 - mu, d1 = v1 - mu;
  float ss = waveSum(d0*d0 + d1*d1);
  if ((tid & 63) == 0) red[tid >> 6] = ss;
  __syncthreads();
  float inv = rsqrtf((red[0] + red[1] + red[2] + red[3]) * (1.f/512.f) + 1e-5f);
  Xb[(size_t)row*D_ + tid]       = f2b(d0 * inv * g[tid]       + b[tid]);
  Xb[(size_t)row*D_ + tid + 256] = f2b(d1 * inv * g[tid + 256] + b[tid + 256]);
}

// ---------------- head: Xq[row](bf16) @ W_head[512,32] + b_head --------------------
__global__ __launch_bounds__(64) void head_kernel(
    const unsigned short* __restrict__ Xq, const float* __restrict__ W_head,
    const float* __restrict__ b_head, float* __restrict__ out)
{
  int row = blockIdx.x;            // 0..MQ_-1
  const unsigned short* xr = Xq + (size_t)row*D_;
  __shared__ float xs[512];
  int tid = threadIdx.x;
  for (int i = tid; i < 512; i += 64) xs[i] = b2f(xr[i]);
  __syncthreads();
  if (tid < 32) {
    float acc = b_head[tid];
    #pragma unroll 8
    for (int k = 0; k < 512; k++) acc += xs[k] * W_head[k*32 + tid];
    out[(size_t)row*32 + tid] = acc;
  }
}

extern "C" void kernel_launch(void* const* d_in, const int* in_sizes, int n_in,
                              void* d_out, int out_size, void* d_ws, size_t ws_size,
                              hipStream_t stream)
{
  const float* x_c      = (const float*)d_in[0];
  const float* y_c      = (const float*)d_in[1];
  const float* x_q      = (const float*)d_in[2];
  const float* W_val    = (const float*)d_in[3];
  const float* b_val    = (const float*)d_in[4];
  const float* q_emb    = (const float*)d_in[5];
  const float* in_proj_w= (const float*)d_in[6];
  const float* in_proj_b= (const float*)d_in[7];
  const float* out_w    = (const float*)d_in[8];
  const float* out_b    = (const float*)d_in[9];
  const float* ln1_g    = (const float*)d_in[10];
  const float* ln1_b    = (const float*)d_in[11];
  const float* lin1_w   = (const float*)d_in[12];
  const float* lin1_b   = (const float*)d_in[13];
  const float* lin2_w   = (const float*)d_in[14];
  const float* lin2_b   = (const float*)d_in[15];
  const float* ln2_g    = (const float*)d_in[16];
  const float* ln2_b    = (const float*)d_in[17];
  const float* W_head   = (const float*)d_in[18];
  const float* b_head   = (const float*)d_in[19];
  float* out = (float*)d_out;

  // workspace layout; residual stream bf16 (Xb1/Xb2), Yb = pre-LN bf16
  char* p = (char*)d_ws;
  unsigned short* Yb   = (unsigned short*)p; p += (size_t)M_*D_*2;    // GEMM+res out (bf16)
  unsigned short* hid  = (unsigned short*)p; p += (size_t)M_*HID_*2;
  unsigned short* Xb2  = (unsigned short*)p; p += (size_t)M_*D_*2;    // ln2/embed out
  unsigned short* qkv  = (unsigned short*)p; p += (size_t)M_*3*D_*2;
  unsigned short* Xb1  = qkv;                                          // alias: ln1 out (disjoint live range)
  unsigned short* ctxb = (unsigned short*)p; p += (size_t)M_*D_*2;
  unsigned short* ipwB = (unsigned short*)p; p += (size_t)L_*3*D_*D_*2;
  unsigned short* owB  = (unsigned short*)p; p += (size_t)L_*D_*D_*2;
  unsigned short* w1B  = (unsigned short*)p; p += (size_t)L_*HID_*D_*2;
  unsigned short* w2B  = (unsigned short*)p; p += (size_t)L_*D_*HID_*2;
  unsigned short* XYb  = (unsigned short*)p; p += (size_t)M_*128*2;
  unsigned short* Wemb = (unsigned short*)p; p += (size_t)D_*128*2;
  float* zbias         = (float*)p;          p += 2048*4;
  float* qkvbias       = (float*)p;          p += L_*1536*4;

  // compact layer-6 buffers (alias XYb region, idle post-embed)
  unsigned short* ctxq  = ctxb;                                   // [MQ_,512]
  unsigned short* Ybq   = Yb;                                     // [MQ_,512]
  unsigned short* hidq  = hid;                                    // [MQ_,2048]
  unsigned short* Xqb2  = XYb;                                    // gathered residual
  unsigned short* Xqb1  = XYb + (size_t)MQ_*D_;                   // ln1 out

  (void)hipMemsetAsync(zbias, 0, 2048*4, stream);

  // convert weights to bf16 (Q rows of in_proj pre-scaled by 0.125*log2e)
  f2bq_kernel<<<512, 256, 0, stream>>>(in_proj_w, ipwB, L_*3*D_*D_/4);
  sbias_kernel<<<36, 256, 0, stream>>>(in_proj_b, qkvbias);
  f2b_kernel<<<512, 256, 0, stream>>>(out_w,     owB,  L_*D_*D_/4);
  f2b_kernel<<<512, 256, 0, stream>>>(lin1_w,    w1B,  L_*HID_*D_/4);
  f2b_kernel<<<512, 256, 0, stream>>>(lin2_w,    w2B,  L_*D_*HID_/4);
  wemb_kernel<<<256, 256, 0, stream>>>(W_val, b_val, q_emb, Wemb);
  packxy_kernel<<<1024, 256, 0, stream>>>(x_c, y_c, x_q, XYb);

  // embedding as GEMM (bf16 out -> Xb2)
  bgemm_kernel<0,1><<<dim3(4, 144), 256, 0, stream>>>(
      XYb, Wemb, zbias, nullptr, Xb2, D_, 128);

  for (int l = 0; l < L_ - 1; l++) {
    // QKV projection (bf16 out, scaled Q)
    bgemm_kernel<0,1><<<dim3(12, 144), 256, 0, stream>>>(
        Xb2, ipwB + (size_t)l*3*D_*D_, qkvbias + (size_t)l*3*D_,
        nullptr, qkv, 3*D_, D_);
    // attention (full: 9 q-tiles of 128 per (b,h))
    mattn_kernel<<<B_*H_*9, 256, 0, stream>>>(qkv, ctxb, 9, 0, S_);
    // out-proj + bf16 residual(Xb2) -> Yb bf16  (BK=64)
    bgemm64_kernel<<<dim3(8, 144), 256, 0, stream>>>(
        ctxb, owB + (size_t)l*D_*D_, out_b + (size_t)l*D_, Xb2, Yb, D_, D_);
    ln_kernel<<<M_, 256, 0, stream>>>(Yb, ln1_g + (size_t)l*D_, ln1_b + (size_t)l*D_, Xb1);
    // FFN1 (relu, bf16 out)
    bgemm_kernel<1,1><<<dim3(16, 144), 256, 0, stream>>>(
        Xb1, w1B + (size_t)l*HID_*D_, lin1_b + (size_t)l*HID_,
        nullptr, hid, HID_, D_);
    // FFN2 + bf16 residual(Xb1) -> Yb  (BK=64)
    bgemm64_kernel<<<dim3(8, 144), 256, 0, stream>>>(
        hid, w2B + (size_t)l*D_*HID_, lin2_b + (size_t)l*D_, Xb1, Yb, D_, HID_);
    ln_kernel<<<M_, 256, 0, stream>>>(Yb, ln2_g + (size_t)l*D_, ln2_b + (size_t)l*D_, Xb2);
  }

  // ---------- layer 6 (l = L_-1): only query rows reach the head ----------
  {
    const int l = L_ - 1;
    bgemm_kernel<0,1><<<dim3(12, 144), 256, 0, stream>>>(
        Xb2, ipwB + (size_t)l*3*D_*D_, qkvbias + (size_t)l*3*D_,
        nullptr, qkv, 3*D_, D_);
    // attention only for the query q-tile (128 rows) per (b,h); compact out [MQ_,512]
    mattn_kernel<<<B_*H_, 256, 0, stream>>>(qkv, ctxq, 1, C_, Q_);
    // gather query rows of Xb2 -> Xqb2 (bf16)
    gatherq_kernel<<<MQ_, 256, 0, stream>>>(Xb2, Xqb2);
    // out-proj + residual(Xqb2) -> Ybq (M = 2048)
    bgemm64_kernel<<<dim3(8, 16), 256, 0, stream>>>(
        ctxq, owB + (size_t)l*D_*D_, out_b + (size_t)l*D_, Xqb2, Ybq, D_, D_);
    ln_kernel<<<MQ_, 256, 0, stream>>>(Ybq, ln1_g + (size_t)l*D_, ln1_b + (size_t)l*D_, Xqb1);
    // FFN1 (relu) compact
    bgemm_kernel<1,1><<<dim3(16, 16), 256, 0, stream>>>(
        Xqb1, w1B + (size_t)l*HID_*D_, lin1_b + (size_t)l*HID_,
        nullptr, hidq, HID_, D_);
    // FFN2 + residual(Xqb1) -> Ybq
    bgemm64_kernel<<<dim3(8, 16), 256, 0, stream>>>(
        hidq, w2B + (size_t)l*D_*HID_, lin2_b + (size_t)l*D_, Xqb1, Ybq, D_, HID_);
    // final LN2 -> reuse Xqb2 slot (dead after out-proj)
    ln_kernel<<<MQ_, 256, 0, stream>>>(Ybq, ln2_g + (size_t)l*D_, ln2_b + (size_t)l*D_, Xqb2);
  }

  head_kernel<<<MQ_, 64, 0, stream>>>(Xqb2, W_head, b_head, out);
}

// Round 18
// 1573.751 us; speedup vs baseline: 1.1498x; 1.0043x over previous
//
#include <hip/hip_runtime.h>

#define B_   16
#define C_   1024
#define Q_   128
#define S_   1152
#define D_   512
#define H_   8
#define HID_ 2048
#define L_   6
#define M_   (B_*S_)   // 18432 tokens
#define MQ_  (B_*Q_)   // 2048 query tokens
#define QSC_ 0.18033688011f   // 0.125 * log2(e): folds 1/sqrt(64) and 1/ln2 into Q

typedef short bf16x8 __attribute__((ext_vector_type(8)));
typedef float f32x4  __attribute__((ext_vector_type(4)));
#define MFMA16(a,b,c) __builtin_amdgcn_mfma_f32_16x16x32_bf16(a,b,c,0,0,0)

__device__ __forceinline__ unsigned short f2b(float f){
  union { float f; unsigned u; } v; v.f = f;
  return (unsigned short)((v.u + 0x7FFF + ((v.u >> 16) & 1)) >> 16);  // RNE
}
__device__ __forceinline__ float b2f(unsigned short u){
  return __uint_as_float((unsigned)u << 16);
}
__device__ __forceinline__ void gload16(const void* g, void* l){
  __builtin_amdgcn_global_load_lds((const __attribute__((address_space(1))) void*)g,
                                   (__attribute__((address_space(3))) void*)l, 16, 0, 0);
}
__device__ __forceinline__ float waveSum(float v){
  #pragma unroll
  for (int o = 32; o > 0; o >>= 1) v += __shfl_down(v, o, 64);
  return v;
}

// ---------------- fp32 -> bf16 weight conversion ----------------------------------
__global__ __launch_bounds__(256) void f2b_kernel(
    const float* __restrict__ in, unsigned short* __restrict__ out, int n4)
{
  int i = blockIdx.x*256 + threadIdx.x;
  for (; i < n4; i += gridDim.x*256) {
    float4 v = ((const float4*)in)[i];
    ushort4 o = { f2b(v.x), f2b(v.y), f2b(v.z), f2b(v.w) };
    ((ushort4*)out)[i] = o;
  }
}

// ---------------- in_proj_w -> bf16 with Q-rows pre-scaled by QSC_ -----------------
__global__ __launch_bounds__(256) void f2bq_kernel(
    const float* __restrict__ in, unsigned short* __restrict__ out, int n4)
{
  int i = blockIdx.x*256 + threadIdx.x;
  for (; i < n4; i += gridDim.x*256) {
    const int row = (i >> 7) % 1536;          // 128 float4 per 512-col row
    const float s = (row < 512) ? QSC_ : 1.f;
    float4 v = ((const float4*)in)[i];
    ushort4 o = { f2b(v.x*s), f2b(v.y*s), f2b(v.z*s), f2b(v.w*s) };
    ((ushort4*)out)[i] = o;
  }
}

// ---------------- in_proj_b scaled copy (Q part * QSC_) ----------------------------
__global__ __launch_bounds__(256) void sbias_kernel(
    const float* __restrict__ in, float* __restrict__ out)
{
  int idx = blockIdx.x*256 + threadIdx.x;     // L_*1536 = 9216
  if (idx < L_*1536) {
    int j = idx % 1536;
    out[idx] = in[idx] * (j < 512 ? QSC_ : 1.f);
  }
}

// ---------------- pack XY [M,128] bf16: x | y/0 | 1 | isq | zeros ------------------
__global__ __launch_bounds__(256) void packxy_kernel(
    const float* __restrict__ x_c, const float* __restrict__ y_c,
    const float* __restrict__ x_q, unsigned short* __restrict__ XY)
{
  int idx = blockIdx.x*256 + threadIdx.x;
  const int n = M_*128;
  for (; idx < n; idx += gridDim.x*256) {
    int row = idx >> 7, col = idx & 127;
    int bb = row / S_, s = row % S_;
    float v;
    if (col < 64) {
      v = (s < C_) ? x_c[((size_t)bb*C_ + s)*64 + col]
                   : x_q[((size_t)bb*Q_ + (s - C_))*64 + col];
    } else if (col < 96) {
      v = (s < C_) ? y_c[((size_t)bb*C_ + s)*32 + (col - 64)] : 0.f;
    } else if (col == 96) {
      v = 1.f;
    } else if (col == 97) {
      v = (s >= C_) ? 1.f : 0.f;
    } else v = 0.f;
    XY[idx] = f2b(v);
  }
}

// ---------------- build Wemb [512][128] bf16 (W_val^T | b_val | q_emb | 0) ---------
__global__ __launch_bounds__(256) void wemb_kernel(
    const float* __restrict__ W_val, const float* __restrict__ b_val,
    const float* __restrict__ q_emb, unsigned short* __restrict__ Wemb)
{
  int idx = blockIdx.x*256 + threadIdx.x;   // 512*128 = 65536 = 256*256
  int nn = idx >> 7, k = idx & 127;
  float v;
  if (k < 96)       v = W_val[k*D_ + nn];
  else if (k == 96) v = b_val[nn];
  else if (k == 97) v = q_emb[nn];
  else              v = 0.f;
  Wemb[idx] = f2b(v);
}

// ---------------- gather query rows (bf16) -> compact [MQ_,512] --------------------
__global__ __launch_bounds__(256) void gatherq_kernel(
    const unsigned short* __restrict__ X, unsigned short* __restrict__ Xq)
{
  int row = blockIdx.x;                 // 0..MQ_-1
  int bb = row >> 7, qi = row & 127;
  const unsigned short* src = X + ((size_t)bb*S_ + C_ + qi)*D_;
  unsigned short* dst = Xq + (size_t)row*D_;
  int tid = threadIdx.x;
  dst[tid] = src[tid];
  dst[tid + 256] = src[tid + 256];
}

// T2 swizzle (BK=32 kernels): LDS slot (row, c in 0..3) holds global chunk c ^ SWZ(row)
#define SWZ(row) (((row) >> 1) & 3)
// T2 swizzle (BK=64 kernel): 8 chunks of 16B per 128B row; slot c holds chunk c ^ (row&7)

// ---------------- bf16 MFMA GEMM, 2-phase double-buffered, 128x128 tile, BK=32 -----
// BOUT: 0 = f32 out, 1 = bf16 out.
template<int RELU, int BOUT>
__global__ __launch_bounds__(256) void bgemm_kernel(
    const unsigned short* __restrict__ A, const unsigned short* __restrict__ W,
    const float* __restrict__ bias,
    float* __restrict__ Cf, unsigned short* __restrict__ Cb, int Nn, int Kk)
{
  __shared__ short As[2][4096];     // [buf][128][32] bf16
  __shared__ short Bs[2][4096];
  int lin = blockIdx.y * gridDim.x + blockIdx.x;
  const int nwg = gridDim.x * gridDim.y;
  const int cpx = nwg >> 3;
  lin = (lin & 7) * cpx + (lin >> 3);
  const int bm = (lin / gridDim.x) * 128, bn = (lin % gridDim.x) * 128;

  const int tid = threadIdx.x;
  const int w = tid >> 6, lane = tid & 63, l15 = lane & 15, l4 = lane >> 4;
  const int wm = w >> 1, wn = w & 1;
  f32x4 acc[4][4] = {};
  const size_t strA = (size_t)Kk * 2;          // bytes per row
  const char* Abase = (const char*)A + (size_t)bm * strA;
  const char* Wbase = (const char*)W + (size_t)bn * strA;
  const int srow = tid >> 2;
  const int schunk = (tid & 3) ^ SWZ(srow);    // pre-swizzled source chunk
  const size_t soff = (size_t)srow * strA + (size_t)(schunk * 16);
  const int ldsOff = w * 1024;

#define STAGEK(K0, BUF) do { \
    const char* a0_ = Abase + soff + (size_t)(K0)*2; \
    const char* b0_ = Wbase + soff + (size_t)(K0)*2; \
    char* la_ = (char*)As + (BUF)*8192 + ldsOff; \
    char* lb_ = (char*)Bs + (BUF)*8192 + ldsOff; \
    gload16(a0_,            la_); \
    gload16(a0_ + 64*strA,  la_ + 4096); \
    gload16(b0_,            lb_); \
    gload16(b0_ + 64*strA,  lb_ + 4096); \
  } while(0)

  STAGEK(0, 0);
  const int nk = Kk >> 5;
  for (int t = 0; t < nk; t++) {
    __syncthreads();                       // buf[t&1] staged; prior reads done
    if (t + 1 < nk) STAGEK((t+1)*32, (t+1)&1);   // prefetch under this tile's MFMAs
    const short* AsC = (const short*)As + (t&1)*4096;
    const short* BsC = (const short*)Bs + (t&1)*4096;
    bf16x8 af[4], bfr[4];
    #pragma unroll
    for (int mf = 0; mf < 4; mf++) {
      const int ar = wm*64 + mf*16 + l15;
      af[mf] = *(const bf16x8*)(AsC + ar*32 + (l4 ^ SWZ(ar))*8);
    }
    #pragma unroll
    for (int nf = 0; nf < 4; nf++) {
      const int br = wn*64 + nf*16 + l15;
      bfr[nf] = *(const bf16x8*)(BsC + br*32 + (l4 ^ SWZ(br))*8);
    }
    #pragma unroll
    for (int mf = 0; mf < 4; mf++)
      #pragma unroll
      for (int nf = 0; nf < 4; nf++)
        acc[mf][nf] = MFMA16(af[mf], bfr[nf], acc[mf][nf]);
  }
#undef STAGEK

  #pragma unroll
  for (int mf = 0; mf < 4; mf++) {
    #pragma unroll
    for (int nf = 0; nf < 4; nf++) {
      const int ccol = bn + wn*64 + nf*16 + l15;
      const float bv = bias[ccol];
      #pragma unroll
      for (int r = 0; r < 4; r++) {
        const int rrow = bm + wm*64 + mf*16 + l4*4 + r;
        float o = acc[mf][nf][r] + bv;
        if (RELU) o = fmaxf(o, 0.f);
        if (BOUT == 1) Cb[(size_t)rrow*Nn + ccol] = f2b(o);
        else           Cf[(size_t)rrow*Nn + ccol] = o;
      }
    }
  }
}

// ---------------- bf16 MFMA GEMM, 128x64 tile, BK=64, 2-phase dbuf -----------------
// bf16 residual, bf16 out (pre-LN stream). 16 MFMA / 12 ds_read per iter.
__global__ __launch_bounds__(256) void bgemm64_kernel(
    const unsigned short* __restrict__ A, const unsigned short* __restrict__ W,
    const float* __restrict__ bias, const unsigned short* __restrict__ Rsd,
    unsigned short* __restrict__ Cb, int Nn, int Kk)
{
  __shared__ short As[2][8192];     // [buf][128][64] bf16
  __shared__ short Bs[2][4096];     // [buf][64][64]  bf16
  int lin = blockIdx.y * gridDim.x + blockIdx.x;
  const int nwg = gridDim.x * gridDim.y;
  const int cpx = nwg >> 3;
  lin = (lin & 7) * cpx + (lin >> 3);
  const int bm = (lin / gridDim.x) * 128, bn = (lin % gridDim.x) * 64;

  const int tid = threadIdx.x;
  const int w = tid >> 6, lane = tid & 63, l15 = lane & 15, l4 = lane >> 4;
  f32x4 acc[2][4] = {};
  const size_t strA = (size_t)Kk * 2;
  const char* Abase = (const char*)A + (size_t)bm * strA;
  const char* Wbase = (const char*)W + (size_t)bn * strA;
  const int srow = tid >> 3;                   // 0..31 (32 rows per 4KB stage call)
  const int schunk = (tid & 7) ^ (srow & 7);   // pre-swizzled source chunk (16B)
  const size_t soff = (size_t)srow * strA + (size_t)(schunk * 16);
  const int ldsOff = w * 1024;

#define STG64(K0, BUF) do { \
    const char* a0_ = Abase + soff + (size_t)(K0)*2; \
    const char* b0_ = Wbase + soff + (size_t)(K0)*2; \
    char* la_ = (char*)As + (BUF)*16384 + ldsOff; \
    char* lb_ = (char*)Bs + (BUF)*8192  + ldsOff; \
    gload16(a0_,            la_); \
    gload16(a0_ + 32*strA,  la_ + 4096); \
    gload16(a0_ + 64*strA,  la_ + 8192); \
    gload16(a0_ + 96*strA,  la_ + 12288); \
    gload16(b0_,            lb_); \
    gload16(b0_ + 32*strA,  lb_ + 4096); \
  } while(0)

  STG64(0, 0);
  const int nk = Kk >> 6;
  for (int t = 0; t < nk; t++) {
    __syncthreads();                       // buf[t&1] staged; prior reads done
    if (t + 1 < nk) STG64((t+1)*64, (t+1)&1);
    const short* AsC = (const short*)As + (t&1)*8192;
    const short* BsC = (const short*)Bs + (t&1)*4096;
    bf16x8 af[2][2], bfr[4][2];
    #pragma unroll
    for (int mf = 0; mf < 2; mf++) {
      const int ar = w*32 + mf*16 + l15;
      #pragma unroll
      for (int ks = 0; ks < 2; ks++) {
        const int c = ks*4 + l4;
        af[mf][ks] = *(const bf16x8*)(AsC + ar*64 + (c ^ (ar & 7))*8);
      }
    }
    #pragma unroll
    for (int nf = 0; nf < 4; nf++) {
      const int br = nf*16 + l15;
      #pragma unroll
      for (int ks = 0; ks < 2; ks++) {
        const int c = ks*4 + l4;
        bfr[nf][ks] = *(const bf16x8*)(BsC + br*64 + (c ^ (br & 7))*8);
      }
    }
    #pragma unroll
    for (int ks = 0; ks < 2; ks++)
      #pragma unroll
      for (int mf = 0; mf < 2; mf++)
        #pragma unroll
        for (int nf = 0; nf < 4; nf++)
          acc[mf][nf] = MFMA16(af[mf][ks], bfr[nf][ks], acc[mf][nf]);
  }
#undef STG64

  #pragma unroll
  for (int mf = 0; mf < 2; mf++) {
    #pragma unroll
    for (int nf = 0; nf < 4; nf++) {
      const int ccol = bn + nf*16 + l15;
      const float bv = bias[ccol];
      #pragma unroll
      for (int r = 0; r < 4; r++) {
        const int rrow = bm + w*32 + mf*16 + l4*4 + r;
        float o = acc[mf][nf][r] + bv + b2f(Rsd[(size_t)rrow*Nn + ccol]);
        Cb[(size_t)rrow*Nn + ccol] = f2b(o);
      }
    }
  }
}

// ---------------- MFMA flash attention, QBLK=64, base-2 softmax, no running max ----
__global__ __launch_bounds__(256) void mattn_kernel(
    const unsigned short* __restrict__ QKV, unsigned short* __restrict__ Ctx,
    int nqt, int qoff, int orows)
{
  __shared__ short Ks[64*72];      // [key][hd], 144B row stride
  __shared__ short Vt[64*72];      // [hd][key] transposed, slot-XOR swizzled
  __shared__ short Ps[4*16*72];    // per-wave P tile [q][key]
  int bid = blockIdx.x;
  const int nwg = gridDim.x;                 // always % 8 == 0 (2304 or 256)
  bid = (bid & 7) * (nwg >> 3) + (bid >> 3);
  const int qt = bid % nqt;
  const int h  = (bid / nqt) % H_;
  const int bb = bid / (nqt*H_);
  const int tid = threadIdx.x;
  const int w = tid >> 6, lane = tid & 63, l15 = lane & 15, l4 = lane >> 4;

  const size_t rowQ = (size_t)bb*S_ + qoff + (size_t)qt*64 + w*16 + l15;
  const unsigned short* qp = QKV + rowQ*1536 + h*64;
  const bf16x8 qf0 = *(const bf16x8*)(qp + l4*8);
  const bf16x8 qf1 = *(const bf16x8*)(qp + 32 + l4*8);

  const unsigned short* Kg = QKV + (size_t)bb*S_*1536 + 512 + h*64;
  const unsigned short* Vg = Kg + 512;

  f32x4 ctx[4] = {};
  f32x4 lacc = {};                 // row-sum accumulator (all cols identical)

  const bf16x8 onesv = {(short)0x3F80,(short)0x3F80,(short)0x3F80,(short)0x3F80,
                        (short)0x3F80,(short)0x3F80,(short)0x3F80,(short)0x3F80};

  char* PsW = (char*)Ps + w*2304;

  const int skey = tid >> 3, shc = tid & 7;
  const int vp   = tid >> 3, vhc = tid & 7;

  const unsigned short* gK = Kg + (size_t)skey*1536 + shc*8;
  const unsigned short* gV = Vg + (size_t)(2*vp)*1536 + vhc*8;
  bf16x8 k0v = *(const bf16x8*)gK;
  bf16x8 k1v = *(const bf16x8*)(gK + 32*1536);
  bf16x8 c0  = *(const bf16x8*)gV;
  bf16x8 c1  = *(const bf16x8*)(gV + 1536);

  for (int kt = 0; kt < 16; kt++) {
    __syncthreads();
    *(bf16x8*)((char*)Ks + skey*144      + shc*16) = k0v;
    *(bf16x8*)((char*)Ks + (skey+32)*144 + shc*16) = k1v;
    #pragma unroll
    for (int j = 0; j < 8; j++) {
      const int hd = vhc*8 + j;
      unsigned int val = (unsigned int)(unsigned short)c0[j]
                       | ((unsigned int)(unsigned short)c1[j] << 16);
      *(unsigned int*)((char*)Vt + hd*144 + ((4*vp) ^ (vhc<<4))) = val;
    }
    __syncthreads();
    // T14: issue next tile's global loads now; latency hides under compute
    if (kt < 15) {
      const unsigned short* nK = gK + (size_t)(kt+1)*98304;
      const unsigned short* nV = gV + (size_t)(kt+1)*98304;
      k0v = *(const bf16x8*)nK;
      k1v = *(const bf16x8*)(nK + 32*1536);
      c0  = *(const bf16x8*)nV;
      c1  = *(const bf16x8*)(nV + 1536);
    }

    // S = Q K^T  (log2-domain scores; Q pre-scaled)
    f32x4 sac[4] = {};
    __builtin_amdgcn_s_setprio(1);
    #pragma unroll
    for (int nf = 0; nf < 4; nf++) {
      const char* kb = (char*)Ks + (nf*16 + l15)*144 + l4*16;
      bf16x8 b0 = *(const bf16x8*)kb;
      bf16x8 b1 = *(const bf16x8*)(kb + 64);
      sac[nf] = MFMA16(qf0, b0, sac[nf]);
      sac[nf] = MFMA16(qf1, b1, sac[nf]);
    }
    __builtin_amdgcn_s_setprio(0);

    // P = exp2(s) -> LDS truncated bf16 (no max subtraction needed)
    #pragma unroll
    for (int r = 0; r < 4; r++) {
      unsigned short* pw = (unsigned short*)(PsW + (l4*4 + r)*144);
      pw[ 0 + l15] = (unsigned short)(__float_as_uint(__builtin_amdgcn_exp2f(sac[0][r])) >> 16);
      pw[16 + l15] = (unsigned short)(__float_as_uint(__builtin_amdgcn_exp2f(sac[1][r])) >> 16);
      pw[32 + l15] = (unsigned short)(__float_as_uint(__builtin_amdgcn_exp2f(sac[2][r])) >> 16);
      pw[48 + l15] = (unsigned short)(__float_as_uint(__builtin_amdgcn_exp2f(sac[3][r])) >> 16);
    }

    // PV: ctx += P(16xkeys) * V(keys x 64hd); l += P * ones
    const char* pb = PsW + l15*144 + l4*16;
    const bf16x8 pf0 = *(const bf16x8*)pb;
    const bf16x8 pf1 = *(const bf16x8*)(pb + 64);
    __builtin_amdgcn_s_setprio(1);
    lacc = MFMA16(pf0, onesv, lacc);
    lacc = MFMA16(pf1, onesv, lacc);
    #pragma unroll
    for (int hf = 0; hf < 4; hf++) {
      const int hd = hf*16 + l15;
      const int hc = (hd >> 3) & 7;
      const char* vb = (char*)Vt + hd*144;
      bf16x8 v0 = *(const bf16x8*)(vb + ((l4*16)     ^ (hc<<4)));
      bf16x8 v1 = *(const bf16x8*)(vb + (((l4+4)*16) ^ (hc<<4)));
      ctx[hf] = MFMA16(pf0, v0, ctx[hf]);
      ctx[hf] = MFMA16(pf1, v1, ctx[hf]);
    }
    __builtin_amdgcn_s_setprio(0);
  }

  // epilogue: divide by l, store bf16 ctx
  #pragma unroll
  for (int r = 0; r < 4; r++) {
    const float invl = 1.0f / lacc[r];
    const size_t row = (size_t)bb*orows + (size_t)qt*64 + w*16 + l4*4 + r;
    unsigned short* op = Ctx + row*512 + h*64;
    op[ 0 + l15] = f2b(ctx[0][r]*invl);
    op[16 + l15] = f2b(ctx[1][r]*invl);
    op[32 + l15] = f2b(ctx[2][r]*invl);
    op[48 + l15] = f2b(ctx[3][r]*invl);
  }
}

// ---------------- row LayerNorm over D=512: bf16 in, bf16 out ----------------------
__global__ __launch_bounds__(256) void ln_kernel(
    const unsigned short* __restrict__ Yin, const float* __restrict__ g, const float* __restrict__ b,
    unsigned short* __restrict__ Xb)
{
  int row = blockIdx.x, tid = threadIdx.x;
  const unsigned short* yr = Yin + (size_t)row*D_;
  float v0 = b2f(yr[tid]), v1 = b2f(yr[tid + 256]);
  __shared__ float red[4];
  float s = waveSum(v0 + v1);
  if ((tid & 63) == 0) red[tid >> 6] = s;
  __syncthreads();
  float mu = (red[0] + red[1] + red[2] + red[3]) * (1.f/512.f);
  __syncthreads();
  float d0 = v0 - mu, d1 = v1 - mu;
  float ss = waveSum(d0*d0 + d1*d1);
  if ((tid & 63) == 0) red[tid >> 6] = ss;
  __syncthreads();
  float inv = rsqrtf((red[0] + red[1] + red[2] + red[3]) * (1.f/512.f) + 1e-5f);
  Xb[(size_t)row*D_ + tid]       = f2b(d0 * inv * g[tid]       + b[tid]);
  Xb[(size_t)row*D_ + tid + 256] = f2b(d1 * inv * g[tid + 256] + b[tid + 256]);
}

// ---------------- head: Xq[row](bf16) @ W_head[512,32] + b_head --------------------
__global__ __launch_bounds__(64) void head_kernel(
    const unsigned short* __restrict__ Xq, const float* __restrict__ W_head,
    const float* __restrict__ b_head, float* __restrict__ out)
{
  int row = blockIdx.x;            // 0..MQ_-1
  const unsigned short* xr = Xq + (size_t)row*D_;
  __shared__ float xs[512];
  int tid = threadIdx.x;
  for (int i = tid; i < 512; i += 64) xs[i] = b2f(xr[i]);
  __syncthreads();
  if (tid < 32) {
    float acc = b_head[tid];
    #pragma unroll 8
    for (int k = 0; k < 512; k++) acc += xs[k] * W_head[k*32 + tid];
    out[(size_t)row*32 + tid] = acc;
  }
}

extern "C" void kernel_launch(void* const* d_in, const int* in_sizes, int n_in,
                              void* d_out, int out_size, void* d_ws, size_t ws_size,
                              hipStream_t stream)
{
  const float* x_c      = (const float*)d_in[0];
  const float* y_c      = (const float*)d_in[1];
  const float* x_q      = (const float*)d_in[2];
  const float* W_val    = (const float*)d_in[3];
  const float* b_val    = (const float*)d_in[4];
  const float* q_emb    = (const float*)d_in[5];
  const float* in_proj_w= (const float*)d_in[6];
  const float* in_proj_b= (const float*)d_in[7];
  const float* out_w    = (const float*)d_in[8];
  const float* out_b    = (const float*)d_in[9];
  const float* ln1_g    = (const float*)d_in[10];
  const float* ln1_b    = (const float*)d_in[11];
  const float* lin1_w   = (const float*)d_in[12];
  const float* lin1_b   = (const float*)d_in[13];
  const float* lin2_w   = (const float*)d_in[14];
  const float* lin2_b   = (const float*)d_in[15];
  const float* ln2_g    = (const float*)d_in[16];
  const float* ln2_b    = (const float*)d_in[17];
  const float* W_head   = (const float*)d_in[18];
  const float* b_head   = (const float*)d_in[19];
  float* out = (float*)d_out;

  // workspace layout; residual stream bf16 (Xb1/Xb2), Yb = pre-LN bf16
  char* p = (char*)d_ws;
  unsigned short* Yb   = (unsigned short*)p; p += (size_t)M_*D_*2;    // GEMM+res out (bf16)
  unsigned short* hid  = (unsigned short*)p; p += (size_t)M_*HID_*2;
  unsigned short* Xb2  = (unsigned short*)p; p += (size_t)M_*D_*2;    // ln2/embed out
  unsigned short* qkv  = (unsigned short*)p; p += (size_t)M_*3*D_*2;
  unsigned short* Xb1  = qkv;                                          // alias: ln1 out (disjoint live range)
  unsigned short* ctxb = (unsigned short*)p; p += (size_t)M_*D_*2;
  unsigned short* ipwB = (unsigned short*)p; p += (size_t)L_*3*D_*D_*2;
  unsigned short* owB  = (unsigned short*)p; p += (size_t)L_*D_*D_*2;
  unsigned short* w1B  = (unsigned short*)p; p += (size_t)L_*HID_*D_*2;
  unsigned short* w2B  = (unsigned short*)p; p += (size_t)L_*D_*HID_*2;
  unsigned short* XYb  = (unsigned short*)p; p += (size_t)M_*128*2;
  unsigned short* Wemb = (unsigned short*)p; p += (size_t)D_*128*2;
  float* zbias         = (float*)p;          p += 2048*4;
  float* qkvbias       = (float*)p;          p += L_*1536*4;

  // compact layer-6 buffers (alias XYb region, idle post-embed)
  unsigned short* ctxq  = ctxb;                                   // [MQ_,512]
  unsigned short* Ybq   = Yb;                                     // [MQ_,512]
  unsigned short* hidq  = hid;                                    // [MQ_,2048]
  unsigned short* Xqb2  = XYb;                                    // gathered residual
  unsigned short* Xqb1  = XYb + (size_t)MQ_*D_;                   // ln1 out

  (void)hipMemsetAsync(zbias, 0, 2048*4, stream);

  // convert weights to bf16 (Q rows of in_proj pre-scaled by 0.125*log2e)
  f2bq_kernel<<<512, 256, 0, stream>>>(in_proj_w, ipwB, L_*3*D_*D_/4);
  sbias_kernel<<<36, 256, 0, stream>>>(in_proj_b, qkvbias);
  f2b_kernel<<<512, 256, 0, stream>>>(out_w,     owB,  L_*D_*D_/4);
  f2b_kernel<<<512, 256, 0, stream>>>(lin1_w,    w1B,  L_*HID_*D_/4);
  f2b_kernel<<<512, 256, 0, stream>>>(lin2_w,    w2B,  L_*D_*HID_/4);
  wemb_kernel<<<256, 256, 0, stream>>>(W_val, b_val, q_emb, Wemb);
  packxy_kernel<<<1024, 256, 0, stream>>>(x_c, y_c, x_q, XYb);

  // embedding as GEMM (bf16 out -> Xb2)
  bgemm_kernel<0,1><<<dim3(4, 144), 256, 0, stream>>>(
      XYb, Wemb, zbias, nullptr, Xb2, D_, 128);

  for (int l = 0; l < L_ - 1; l++) {
    // QKV projection (bf16 out, scaled Q)
    bgemm_kernel<0,1><<<dim3(12, 144), 256, 0, stream>>>(
        Xb2, ipwB + (size_t)l*3*D_*D_, qkvbias + (size_t)l*3*D_,
        nullptr, qkv, 3*D_, D_);
    // attention (full: 18 q-tiles per (b,h))
    mattn_kernel<<<B_*H_*18, 256, 0, stream>>>(qkv, ctxb, 18, 0, S_);
    // out-proj + bf16 residual(Xb2) -> Yb bf16  (BK=64)
    bgemm64_kernel<<<dim3(8, 144), 256, 0, stream>>>(
        ctxb, owB + (size_t)l*D_*D_, out_b + (size_t)l*D_, Xb2, Yb, D_, D_);
    ln_kernel<<<M_, 256, 0, stream>>>(Yb, ln1_g + (size_t)l*D_, ln1_b + (size_t)l*D_, Xb1);
    // FFN1 (relu, bf16 out)
    bgemm_kernel<1,1><<<dim3(16, 144), 256, 0, stream>>>(
        Xb1, w1B + (size_t)l*HID_*D_, lin1_b + (size_t)l*HID_,
        nullptr, hid, HID_, D_);
    // FFN2 + bf16 residual(Xb1) -> Yb  (BK=64)
    bgemm64_kernel<<<dim3(8, 144), 256, 0, stream>>>(
        hid, w2B + (size_t)l*D_*HID_, lin2_b + (size_t)l*D_, Xb1, Yb, D_, HID_);
    ln_kernel<<<M_, 256, 0, stream>>>(Yb, ln2_g + (size_t)l*D_, ln2_b + (size_t)l*D_, Xb2);
  }

  // ---------- layer 6 (l = L_-1): only query rows reach the head ----------
  {
    const int l = L_ - 1;
    bgemm_kernel<0,1><<<dim3(12, 144), 256, 0, stream>>>(
        Xb2, ipwB + (size_t)l*3*D_*D_, qkvbias + (size_t)l*3*D_,
        nullptr, qkv, 3*D_, D_);
    // attention only for the 2 query q-tiles per (b,h); compact output [MQ_,512]
    mattn_kernel<<<B_*H_*2, 256, 0, stream>>>(qkv, ctxq, 2, C_, Q_);
    // gather query rows of Xb2 -> Xqb2 (bf16)
    gatherq_kernel<<<MQ_, 256, 0, stream>>>(Xb2, Xqb2);
    // out-proj + residual(Xqb2) -> Ybq (M = 2048)
    bgemm64_kernel<<<dim3(8, 16), 256, 0, stream>>>(
        ctxq, owB + (size_t)l*D_*D_, out_b + (size_t)l*D_, Xqb2, Ybq, D_, D_);
    ln_kernel<<<MQ_, 256, 0, stream>>>(Ybq, ln1_g + (size_t)l*D_, ln1_b + (size_t)l*D_, Xqb1);
    // FFN1 (relu) compact
    bgemm_kernel<1,1><<<dim3(16, 16), 256, 0, stream>>>(
        Xqb1, w1B + (size_t)l*HID_*D_, lin1_b + (size_t)l*HID_,
        nullptr, hidq, HID_, D_);
    // FFN2 + residual(Xqb1) -> Ybq
    bgemm64_kernel<<<dim3(8, 16), 256, 0, stream>>>(
        hidq, w2B + (size_t)l*D_*HID_, lin2_b + (size_t)l*D_, Xqb1, Ybq, D_, HID_);
    // final LN2 -> reuse Xqb2 slot (dead after out-proj)
    ln_kernel<<<MQ_, 256, 0, stream>>>(Ybq, ln2_g + (size_t)l*D_, ln2_b + (size_t)l*D_, Xqb2);
  }

  head_kernel<<<MQ_, 64, 0, stream>>>(Xqb2, W_head, b_head, out);
}

// Round 19
// 1570.422 us; speedup vs baseline: 1.1522x; 1.0021x over previous
//
#include <hip/hip_runtime.h>

#define B_   16
#define C_   1024
#define Q_   128
#define S_   1152
#define D_   512
#define H_   8
#define HID_ 2048
#define L_   6
#define M_   (B_*S_)   // 18432 tokens
#define MQ_  (B_*Q_)   // 2048 query tokens
#define QSC_ 0.18033688011f   // 0.125 * log2(e): folds 1/sqrt(64) and 1/ln2 into Q

typedef short bf16x8 __attribute__((ext_vector_type(8)));
typedef float f32x4  __attribute__((ext_vector_type(4)));
#define MFMA16(a,b,c) __builtin_amdgcn_mfma_f32_16x16x32_bf16(a,b,c,0,0,0)

__device__ __forceinline__ unsigned short f2b(float f){
  union { float f; unsigned u; } v; v.f = f;
  return (unsigned short)((v.u + 0x7FFF + ((v.u >> 16) & 1)) >> 16);  // RNE
}
__device__ __forceinline__ float b2f(unsigned short u){
  return __uint_as_float((unsigned)u << 16);
}
__device__ __forceinline__ void gload16(const void* g, void* l){
  __builtin_amdgcn_global_load_lds((const __attribute__((address_space(1))) void*)g,
                                   (__attribute__((address_space(3))) void*)l, 16, 0, 0);
}
__device__ __forceinline__ float waveSum(float v){
  #pragma unroll
  for (int o = 32; o > 0; o >>= 1) v += __shfl_down(v, o, 64);
  return v;
}

// ---------------- fp32 -> bf16 weight conversion ----------------------------------
__global__ __launch_bounds__(256) void f2b_kernel(
    const float* __restrict__ in, unsigned short* __restrict__ out, int n4)
{
  int i = blockIdx.x*256 + threadIdx.x;
  for (; i < n4; i += gridDim.x*256) {
    float4 v = ((const float4*)in)[i];
    ushort4 o = { f2b(v.x), f2b(v.y), f2b(v.z), f2b(v.w) };
    ((ushort4*)out)[i] = o;
  }
}

// ---------------- in_proj_w -> bf16 with Q-rows pre-scaled by QSC_ -----------------
__global__ __launch_bounds__(256) void f2bq_kernel(
    const float* __restrict__ in, unsigned short* __restrict__ out, int n4)
{
  int i = blockIdx.x*256 + threadIdx.x;
  for (; i < n4; i += gridDim.x*256) {
    const int row = (i >> 7) % 1536;          // 128 float4 per 512-col row
    const float s = (row < 512) ? QSC_ : 1.f;
    float4 v = ((const float4*)in)[i];
    ushort4 o = { f2b(v.x*s), f2b(v.y*s), f2b(v.z*s), f2b(v.w*s) };
    ((ushort4*)out)[i] = o;
  }
}

// ---------------- in_proj_b scaled copy (Q part * QSC_) ----------------------------
__global__ __launch_bounds__(256) void sbias_kernel(
    const float* __restrict__ in, float* __restrict__ out)
{
  int idx = blockIdx.x*256 + threadIdx.x;     // L_*1536 = 9216
  if (idx < L_*1536) {
    int j = idx % 1536;
    out[idx] = in[idx] * (j < 512 ? QSC_ : 1.f);
  }
}

// ---------------- pack XY [M,128] bf16: x | y/0 | 1 | isq | zeros ------------------
__global__ __launch_bounds__(256) void packxy_kernel(
    const float* __restrict__ x_c, const float* __restrict__ y_c,
    const float* __restrict__ x_q, unsigned short* __restrict__ XY)
{
  int idx = blockIdx.x*256 + threadIdx.x;
  const int n = M_*128;
  for (; idx < n; idx += gridDim.x*256) {
    int row = idx >> 7, col = idx & 127;
    int bb = row / S_, s = row % S_;
    float v;
    if (col < 64) {
      v = (s < C_) ? x_c[((size_t)bb*C_ + s)*64 + col]
                   : x_q[((size_t)bb*Q_ + (s - C_))*64 + col];
    } else if (col < 96) {
      v = (s < C_) ? y_c[((size_t)bb*C_ + s)*32 + (col - 64)] : 0.f;
    } else if (col == 96) {
      v = 1.f;
    } else if (col == 97) {
      v = (s >= C_) ? 1.f : 0.f;
    } else v = 0.f;
    XY[idx] = f2b(v);
  }
}

// ---------------- build Wemb [512][128] bf16 (W_val^T | b_val | q_emb | 0) ---------
__global__ __launch_bounds__(256) void wemb_kernel(
    const float* __restrict__ W_val, const float* __restrict__ b_val,
    const float* __restrict__ q_emb, unsigned short* __restrict__ Wemb)
{
  int idx = blockIdx.x*256 + threadIdx.x;   // 512*128 = 65536 = 256*256
  int nn = idx >> 7, k = idx & 127;
  float v;
  if (k < 96)       v = W_val[k*D_ + nn];
  else if (k == 96) v = b_val[nn];
  else if (k == 97) v = q_emb[nn];
  else              v = 0.f;
  Wemb[idx] = f2b(v);
}

// ---------------- gather query rows (bf16) -> compact [MQ_,512] --------------------
__global__ __launch_bounds__(256) void gatherq_kernel(
    const unsigned short* __restrict__ X, unsigned short* __restrict__ Xq)
{
  int row = blockIdx.x;                 // 0..MQ_-1
  int bb = row >> 7, qi = row & 127;
  const unsigned short* src = X + ((size_t)bb*S_ + C_ + qi)*D_;
  unsigned short* dst = Xq + (size_t)row*D_;
  int tid = threadIdx.x;
  dst[tid] = src[tid];
  dst[tid + 256] = src[tid + 256];
}

// T2 swizzle (BK=32 kernel): LDS slot (row, c in 0..3) holds global chunk c ^ SWZ(row)
#define SWZ(row) (((row) >> 1) & 3)
// T2 swizzle (BK=64 kernels): 8 chunks of 16B per 128B row; slot c holds chunk c ^ (row&7)

// ---------------- bf16 MFMA GEMM, 2-phase dbuf, 128x128 tile, BK=32 (embed) --------
template<int RELU, int BOUT>
__global__ __launch_bounds__(256) void bgemm_kernel(
    const unsigned short* __restrict__ A, const unsigned short* __restrict__ W,
    const float* __restrict__ bias,
    float* __restrict__ Cf, unsigned short* __restrict__ Cb, int Nn, int Kk)
{
  __shared__ short As[2][4096];     // [buf][128][32] bf16
  __shared__ short Bs[2][4096];
  int lin = blockIdx.y * gridDim.x + blockIdx.x;
  const int nwg = gridDim.x * gridDim.y;
  const int cpx = nwg >> 3;
  lin = (lin & 7) * cpx + (lin >> 3);
  const int bm = (lin / gridDim.x) * 128, bn = (lin % gridDim.x) * 128;

  const int tid = threadIdx.x;
  const int w = tid >> 6, lane = tid & 63, l15 = lane & 15, l4 = lane >> 4;
  const int wm = w >> 1, wn = w & 1;
  f32x4 acc[4][4] = {};
  const size_t strA = (size_t)Kk * 2;          // bytes per row
  const char* Abase = (const char*)A + (size_t)bm * strA;
  const char* Wbase = (const char*)W + (size_t)bn * strA;
  const int srow = tid >> 2;
  const int schunk = (tid & 3) ^ SWZ(srow);    // pre-swizzled source chunk
  const size_t soff = (size_t)srow * strA + (size_t)(schunk * 16);
  const int ldsOff = w * 1024;

#define STAGEK(K0, BUF) do { \
    const char* a0_ = Abase + soff + (size_t)(K0)*2; \
    const char* b0_ = Wbase + soff + (size_t)(K0)*2; \
    char* la_ = (char*)As + (BUF)*8192 + ldsOff; \
    char* lb_ = (char*)Bs + (BUF)*8192 + ldsOff; \
    gload16(a0_,            la_); \
    gload16(a0_ + 64*strA,  la_ + 4096); \
    gload16(b0_,            lb_); \
    gload16(b0_ + 64*strA,  lb_ + 4096); \
  } while(0)

  STAGEK(0, 0);
  const int nk = Kk >> 5;
  for (int t = 0; t < nk; t++) {
    __syncthreads();                       // buf[t&1] staged; prior reads done
    if (t + 1 < nk) STAGEK((t+1)*32, (t+1)&1);   // prefetch under this tile's MFMAs
    const short* AsC = (const short*)As + (t&1)*4096;
    const short* BsC = (const short*)Bs + (t&1)*4096;
    bf16x8 af[4], bfr[4];
    #pragma unroll
    for (int mf = 0; mf < 4; mf++) {
      const int ar = wm*64 + mf*16 + l15;
      af[mf] = *(const bf16x8*)(AsC + ar*32 + (l4 ^ SWZ(ar))*8);
    }
    #pragma unroll
    for (int nf = 0; nf < 4; nf++) {
      const int br = wn*64 + nf*16 + l15;
      bfr[nf] = *(const bf16x8*)(BsC + br*32 + (l4 ^ SWZ(br))*8);
    }
    #pragma unroll
    for (int mf = 0; mf < 4; mf++)
      #pragma unroll
      for (int nf = 0; nf < 4; nf++)
        acc[mf][nf] = MFMA16(af[mf], bfr[nf], acc[mf][nf]);
  }
#undef STAGEK

  #pragma unroll
  for (int mf = 0; mf < 4; mf++) {
    #pragma unroll
    for (int nf = 0; nf < 4; nf++) {
      const int ccol = bn + wn*64 + nf*16 + l15;
      const float bv = bias[ccol];
      #pragma unroll
      for (int r = 0; r < 4; r++) {
        const int rrow = bm + wm*64 + mf*16 + l4*4 + r;
        float o = acc[mf][nf][r] + bv;
        if (RELU) o = fmaxf(o, 0.f);
        if (BOUT == 1) Cb[(size_t)rrow*Nn + ccol] = f2b(o);
        else           Cf[(size_t)rrow*Nn + ccol] = o;
      }
    }
  }
}

// ---------------- bf16 MFMA GEMM, 128x128 tile, BK=64, 2-phase dbuf (QKV/FFN1) -----
// bf16 out. 32 MFMA / 16 ds_read per iter; 8-chunk XOR swizzle. 64 KB LDS.
template<int RELU>
__global__ __launch_bounds__(256) void bgemm128k64_kernel(
    const unsigned short* __restrict__ A, const unsigned short* __restrict__ W,
    const float* __restrict__ bias,
    unsigned short* __restrict__ Cb, int Nn, int Kk)
{
  __shared__ short As[2][8192];     // [buf][128][64] bf16 (16 KB/buf)
  __shared__ short Bs[2][8192];
  int lin = blockIdx.y * gridDim.x + blockIdx.x;
  const int nwg = gridDim.x * gridDim.y;
  const int cpx = nwg >> 3;
  lin = (lin & 7) * cpx + (lin >> 3);
  const int bm = (lin / gridDim.x) * 128, bn = (lin % gridDim.x) * 128;

  const int tid = threadIdx.x;
  const int w = tid >> 6, lane = tid & 63, l15 = lane & 15, l4 = lane >> 4;
  const int wm = w >> 1, wn = w & 1;
  f32x4 acc[4][4] = {};
  const size_t strA = (size_t)Kk * 2;
  const char* Abase = (const char*)A + (size_t)bm * strA;
  const char* Wbase = (const char*)W + (size_t)bn * strA;
  const int srow = tid >> 3;                   // 0..31
  const int schunk = (tid & 7) ^ (srow & 7);   // pre-swizzled 16B chunk
  const size_t soff = (size_t)srow * strA + (size_t)(schunk * 16);
  const int ldsOff = w * 1024;

#define STG128(K0, BUF) do { \
    const char* a0_ = Abase + soff + (size_t)(K0)*2; \
    const char* b0_ = Wbase + soff + (size_t)(K0)*2; \
    char* la_ = (char*)As + (BUF)*16384 + ldsOff; \
    char* lb_ = (char*)Bs + (BUF)*16384 + ldsOff; \
    gload16(a0_,            la_); \
    gload16(a0_ + 32*strA,  la_ + 4096); \
    gload16(a0_ + 64*strA,  la_ + 8192); \
    gload16(a0_ + 96*strA,  la_ + 12288); \
    gload16(b0_,            lb_); \
    gload16(b0_ + 32*strA,  lb_ + 4096); \
    gload16(b0_ + 64*strA,  lb_ + 8192); \
    gload16(b0_ + 96*strA,  lb_ + 12288); \
  } while(0)

  STG128(0, 0);
  const int nk = Kk >> 6;
  for (int t = 0; t < nk; t++) {
    __syncthreads();
    if (t + 1 < nk) STG128((t+1)*64, (t+1)&1);
    const short* AsC = (const short*)As + (t&1)*8192;
    const short* BsC = (const short*)Bs + (t&1)*8192;
    bf16x8 af[4][2], bfr[4][2];
    #pragma unroll
    for (int mf = 0; mf < 4; mf++) {
      const int ar = wm*64 + mf*16 + l15;
      #pragma unroll
      for (int ks = 0; ks < 2; ks++) {
        const int c = ks*4 + l4;
        af[mf][ks] = *(const bf16x8*)(AsC + ar*64 + (c ^ (ar & 7))*8);
      }
    }
    #pragma unroll
    for (int nf = 0; nf < 4; nf++) {
      const int br = wn*64 + nf*16 + l15;
      #pragma unroll
      for (int ks = 0; ks < 2; ks++) {
        const int c = ks*4 + l4;
        bfr[nf][ks] = *(const bf16x8*)(BsC + br*64 + (c ^ (br & 7))*8);
      }
    }
    #pragma unroll
    for (int ks = 0; ks < 2; ks++)
      #pragma unroll
      for (int mf = 0; mf < 4; mf++)
        #pragma unroll
        for (int nf = 0; nf < 4; nf++)
          acc[mf][nf] = MFMA16(af[mf][ks], bfr[nf][ks], acc[mf][nf]);
  }
#undef STG128

  #pragma unroll
  for (int mf = 0; mf < 4; mf++) {
    #pragma unroll
    for (int nf = 0; nf < 4; nf++) {
      const int ccol = bn + wn*64 + nf*16 + l15;
      const float bv = bias[ccol];
      #pragma unroll
      for (int r = 0; r < 4; r++) {
        const int rrow = bm + wm*64 + mf*16 + l4*4 + r;
        float o = acc[mf][nf][r] + bv;
        if (RELU) o = fmaxf(o, 0.f);
        Cb[(size_t)rrow*Nn + ccol] = f2b(o);
      }
    }
  }
}

// ---------------- bf16 MFMA GEMM, 128x64 tile, BK=64, 2-phase dbuf -----------------
// bf16 residual, bf16 out (pre-LN stream). 16 MFMA / 12 ds_read per iter.
__global__ __launch_bounds__(256) void bgemm64_kernel(
    const unsigned short* __restrict__ A, const unsigned short* __restrict__ W,
    const float* __restrict__ bias, const unsigned short* __restrict__ Rsd,
    unsigned short* __restrict__ Cb, int Nn, int Kk)
{
  __shared__ short As[2][8192];     // [buf][128][64] bf16
  __shared__ short Bs[2][4096];     // [buf][64][64]  bf16
  int lin = blockIdx.y * gridDim.x + blockIdx.x;
  const int nwg = gridDim.x * gridDim.y;
  const int cpx = nwg >> 3;
  lin = (lin & 7) * cpx + (lin >> 3);
  const int bm = (lin / gridDim.x) * 128, bn = (lin % gridDim.x) * 64;

  const int tid = threadIdx.x;
  const int w = tid >> 6, lane = tid & 63, l15 = lane & 15, l4 = lane >> 4;
  f32x4 acc[2][4] = {};
  const size_t strA = (size_t)Kk * 2;
  const char* Abase = (const char*)A + (size_t)bm * strA;
  const char* Wbase = (const char*)W + (size_t)bn * strA;
  const int srow = tid >> 3;                   // 0..31 (32 rows per 4KB stage call)
  const int schunk = (tid & 7) ^ (srow & 7);   // pre-swizzled source chunk (16B)
  const size_t soff = (size_t)srow * strA + (size_t)(schunk * 16);
  const int ldsOff = w * 1024;

#define STG64(K0, BUF) do { \
    const char* a0_ = Abase + soff + (size_t)(K0)*2; \
    const char* b0_ = Wbase + soff + (size_t)(K0)*2; \
    char* la_ = (char*)As + (BUF)*16384 + ldsOff; \
    char* lb_ = (char*)Bs + (BUF)*8192  + ldsOff; \
    gload16(a0_,            la_); \
    gload16(a0_ + 32*strA,  la_ + 4096); \
    gload16(a0_ + 64*strA,  la_ + 8192); \
    gload16(a0_ + 96*strA,  la_ + 12288); \
    gload16(b0_,            lb_); \
    gload16(b0_ + 32*strA,  lb_ + 4096); \
  } while(0)

  STG64(0, 0);
  const int nk = Kk >> 6;
  for (int t = 0; t < nk; t++) {
    __syncthreads();                       // buf[t&1] staged; prior reads done
    if (t + 1 < nk) STG64((t+1)*64, (t+1)&1);
    const short* AsC = (const short*)As + (t&1)*8192;
    const short* BsC = (const short*)Bs + (t&1)*4096;
    bf16x8 af[2][2], bfr[4][2];
    #pragma unroll
    for (int mf = 0; mf < 2; mf++) {
      const int ar = w*32 + mf*16 + l15;
      #pragma unroll
      for (int ks = 0; ks < 2; ks++) {
        const int c = ks*4 + l4;
        af[mf][ks] = *(const bf16x8*)(AsC + ar*64 + (c ^ (ar & 7))*8);
      }
    }
    #pragma unroll
    for (int nf = 0; nf < 4; nf++) {
      const int br = nf*16 + l15;
      #pragma unroll
      for (int ks = 0; ks < 2; ks++) {
        const int c = ks*4 + l4;
        bfr[nf][ks] = *(const bf16x8*)(BsC + br*64 + (c ^ (br & 7))*8);
      }
    }
    #pragma unroll
    for (int ks = 0; ks < 2; ks++)
      #pragma unroll
      for (int mf = 0; mf < 2; mf++)
        #pragma unroll
        for (int nf = 0; nf < 4; nf++)
          acc[mf][nf] = MFMA16(af[mf][ks], bfr[nf][ks], acc[mf][nf]);
  }
#undef STG64

  #pragma unroll
  for (int mf = 0; mf < 2; mf++) {
    #pragma unroll
    for (int nf = 0; nf < 4; nf++) {
      const int ccol = bn + nf*16 + l15;
      const float bv = bias[ccol];
      #pragma unroll
      for (int r = 0; r < 4; r++) {
        const int rrow = bm + w*32 + mf*16 + l4*4 + r;
        float o = acc[mf][nf][r] + bv + b2f(Rsd[(size_t)rrow*Nn + ccol]);
        Cb[(size_t)rrow*Nn + ccol] = f2b(o);
      }
    }
  }
}

// ---------------- MFMA flash attention, QBLK=64, base-2 softmax, no running max ----
__global__ __launch_bounds__(256) void mattn_kernel(
    const unsigned short* __restrict__ QKV, unsigned short* __restrict__ Ctx,
    int nqt, int qoff, int orows)
{
  __shared__ short Ks[64*72];      // [key][hd], 144B row stride
  __shared__ short Vt[64*72];      // [hd][key] transposed, slot-XOR swizzled
  __shared__ short Ps[4*16*72];    // per-wave P tile [q][key]
  int bid = blockIdx.x;
  const int nwg = gridDim.x;                 // always % 8 == 0 (2304 or 256)
  bid = (bid & 7) * (nwg >> 3) + (bid >> 3);
  const int qt = bid % nqt;
  const int h  = (bid / nqt) % H_;
  const int bb = bid / (nqt*H_);
  const int tid = threadIdx.x;
  const int w = tid >> 6, lane = tid & 63, l15 = lane & 15, l4 = lane >> 4;

  const size_t rowQ = (size_t)bb*S_ + qoff + (size_t)qt*64 + w*16 + l15;
  const unsigned short* qp = QKV + rowQ*1536 + h*64;
  const bf16x8 qf0 = *(const bf16x8*)(qp + l4*8);
  const bf16x8 qf1 = *(const bf16x8*)(qp + 32 + l4*8);

  const unsigned short* Kg = QKV + (size_t)bb*S_*1536 + 512 + h*64;
  const unsigned short* Vg = Kg + 512;

  f32x4 ctx[4] = {};
  f32x4 lacc = {};                 // row-sum accumulator (all cols identical)

  const bf16x8 onesv = {(short)0x3F80,(short)0x3F80,(short)0x3F80,(short)0x3F80,
                        (short)0x3F80,(short)0x3F80,(short)0x3F80,(short)0x3F80};

  char* PsW = (char*)Ps + w*2304;

  const int skey = tid >> 3, shc = tid & 7;
  const int vp   = tid >> 3, vhc = tid & 7;

  const unsigned short* gK = Kg + (size_t)skey*1536 + shc*8;
  const unsigned short* gV = Vg + (size_t)(2*vp)*1536 + vhc*8;
  bf16x8 k0v = *(const bf16x8*)gK;
  bf16x8 k1v = *(const bf16x8*)(gK + 32*1536);
  bf16x8 c0  = *(const bf16x8*)gV;
  bf16x8 c1  = *(const bf16x8*)(gV + 1536);

  for (int kt = 0; kt < 16; kt++) {
    __syncthreads();
    *(bf16x8*)((char*)Ks + skey*144      + shc*16) = k0v;
    *(bf16x8*)((char*)Ks + (skey+32)*144 + shc*16) = k1v;
    #pragma unroll
    for (int j = 0; j < 8; j++) {
      const int hd = vhc*8 + j;
      unsigned int val = (unsigned int)(unsigned short)c0[j]
                       | ((unsigned int)(unsigned short)c1[j] << 16);
      *(unsigned int*)((char*)Vt + hd*144 + ((4*vp) ^ (vhc<<4))) = val;
    }
    __syncthreads();
    // T14: issue next tile's global loads now; latency hides under compute
    if (kt < 15) {
      const unsigned short* nK = gK + (size_t)(kt+1)*98304;
      const unsigned short* nV = gV + (size_t)(kt+1)*98304;
      k0v = *(const bf16x8*)nK;
      k1v = *(const bf16x8*)(nK + 32*1536);
      c0  = *(const bf16x8*)nV;
      c1  = *(const bf16x8*)(nV + 1536);
    }

    // S = Q K^T  (log2-domain scores; Q pre-scaled)
    f32x4 sac[4] = {};
    __builtin_amdgcn_s_setprio(1);
    #pragma unroll
    for (int nf = 0; nf < 4; nf++) {
      const char* kb = (char*)Ks + (nf*16 + l15)*144 + l4*16;
      bf16x8 b0 = *(const bf16x8*)kb;
      bf16x8 b1 = *(const bf16x8*)(kb + 64);
      sac[nf] = MFMA16(qf0, b0, sac[nf]);
      sac[nf] = MFMA16(qf1, b1, sac[nf]);
    }
    __builtin_amdgcn_s_setprio(0);

    // P = exp2(s) -> LDS truncated bf16 (no max subtraction needed)
    #pragma unroll
    for (int r = 0; r < 4; r++) {
      unsigned short* pw = (unsigned short*)(PsW + (l4*4 + r)*144);
      pw[ 0 + l15] = (unsigned short)(__float_as_uint(__builtin_amdgcn_exp2f(sac[0][r])) >> 16);
      pw[16 + l15] = (unsigned short)(__float_as_uint(__builtin_amdgcn_exp2f(sac[1][r])) >> 16);
      pw[32 + l15] = (unsigned short)(__float_as_uint(__builtin_amdgcn_exp2f(sac[2][r])) >> 16);
      pw[48 + l15] = (unsigned short)(__float_as_uint(__builtin_amdgcn_exp2f(sac[3][r])) >> 16);
    }

    // PV: ctx += P(16xkeys) * V(keys x 64hd); l += P * ones
    const char* pb = PsW + l15*144 + l4*16;
    const bf16x8 pf0 = *(const bf16x8*)pb;
    const bf16x8 pf1 = *(const bf16x8*)(pb + 64);
    __builtin_amdgcn_s_setprio(1);
    lacc = MFMA16(pf0, onesv, lacc);
    lacc = MFMA16(pf1, onesv, lacc);
    #pragma unroll
    for (int hf = 0; hf < 4; hf++) {
      const int hd = hf*16 + l15;
      const int hc = (hd >> 3) & 7;
      const char* vb = (char*)Vt + hd*144;
      bf16x8 v0 = *(const bf16x8*)(vb + ((l4*16)     ^ (hc<<4)));
      bf16x8 v1 = *(const bf16x8*)(vb + (((l4+4)*16) ^ (hc<<4)));
      ctx[hf] = MFMA16(pf0, v0, ctx[hf]);
      ctx[hf] = MFMA16(pf1, v1, ctx[hf]);
    }
    __builtin_amdgcn_s_setprio(0);
  }

  // epilogue: divide by l, store bf16 ctx
  #pragma unroll
  for (int r = 0; r < 4; r++) {
    const float invl = 1.0f / lacc[r];
    const size_t row = (size_t)bb*orows + (size_t)qt*64 + w*16 + l4*4 + r;
    unsigned short* op = Ctx + row*512 + h*64;
    op[ 0 + l15] = f2b(ctx[0][r]*invl);
    op[16 + l15] = f2b(ctx[1][r]*invl);
    op[32 + l15] = f2b(ctx[2][r]*invl);
    op[48 + l15] = f2b(ctx[3][r]*invl);
  }
}

// ---------------- row LayerNorm over D=512: bf16 in, bf16 out ----------------------
__global__ __launch_bounds__(256) void ln_kernel(
    const unsigned short* __restrict__ Yin, const float* __restrict__ g, const float* __restrict__ b,
    unsigned short* __restrict__ Xb)
{
  int row = blockIdx.x, tid = threadIdx.x;
  const unsigned short* yr = Yin + (size_t)row*D_;
  float v0 = b2f(yr[tid]), v1 = b2f(yr[tid + 256]);
  __shared__ float red[4];
  float s = waveSum(v0 + v1);
  if ((tid & 63) == 0) red[tid >> 6] = s;
  __syncthreads();
  float mu = (red[0] + red[1] + red[2] + red[3]) * (1.f/512.f);
  __syncthreads();
  float d0 = v0 - mu, d1 = v1 - mu;
  float ss = waveSum(d0*d0 + d1*d1);
  if ((tid & 63) == 0) red[tid >> 6] = ss;
  __syncthreads();
  float inv = rsqrtf((red[0] + red[1] + red[2] + red[3]) * (1.f/512.f) + 1e-5f);
  Xb[(size_t)row*D_ + tid]       = f2b(d0 * inv * g[tid]       + b[tid]);
  Xb[(size_t)row*D_ + tid + 256] = f2b(d1 * inv * g[tid + 256] + b[tid + 256]);
}

// ---------------- head: Xq[row](bf16) @ W_head[512,32] + b_head --------------------
__global__ __launch_bounds__(64) void head_kernel(
    const unsigned short* __restrict__ Xq, const float* __restrict__ W_head,
    const float* __restrict__ b_head, float* __restrict__ out)
{
  int row = blockIdx.x;            // 0..MQ_-1
  const unsigned short* xr = Xq + (size_t)row*D_;
  __shared__ float xs[512];
  int tid = threadIdx.x;
  for (int i = tid; i < 512; i += 64) xs[i] = b2f(xr[i]);
  __syncthreads();
  if (tid < 32) {
    float acc = b_head[tid];
    #pragma unroll 8
    for (int k = 0; k < 512; k++) acc += xs[k] * W_head[k*32 + tid];
    out[(size_t)row*32 + tid] = acc;
  }
}

extern "C" void kernel_launch(void* const* d_in, const int* in_sizes, int n_in,
                              void* d_out, int out_size, void* d_ws, size_t ws_size,
                              hipStream_t stream)
{
  const float* x_c      = (const float*)d_in[0];
  const float* y_c      = (const float*)d_in[1];
  const float* x_q      = (const float*)d_in[2];
  const float* W_val    = (const float*)d_in[3];
  const float* b_val    = (const float*)d_in[4];
  const float* q_emb    = (const float*)d_in[5];
  const float* in_proj_w= (const float*)d_in[6];
  const float* in_proj_b= (const float*)d_in[7];
  const float* out_w    = (const float*)d_in[8];
  const float* out_b    = (const float*)d_in[9];
  const float* ln1_g    = (const float*)d_in[10];
  const float* ln1_b    = (const float*)d_in[11];
  const float* lin1_w   = (const float*)d_in[12];
  const float* lin1_b   = (const float*)d_in[13];
  const float* lin2_w   = (const float*)d_in[14];
  const float* lin2_b   = (const float*)d_in[15];
  const float* ln2_g    = (const float*)d_in[16];
  const float* ln2_b    = (const float*)d_in[17];
  const float* W_head   = (const float*)d_in[18];
  const float* b_head   = (const float*)d_in[19];
  float* out = (float*)d_out;

  // workspace layout; residual stream bf16 (Xb1/Xb2), Yb = pre-LN bf16
  char* p = (char*)d_ws;
  unsigned short* Yb   = (unsigned short*)p; p += (size_t)M_*D_*2;    // GEMM+res out (bf16)
  unsigned short* hid  = (unsigned short*)p; p += (size_t)M_*HID_*2;
  unsigned short* Xb2  = (unsigned short*)p; p += (size_t)M_*D_*2;    // ln2/embed out
  unsigned short* qkv  = (unsigned short*)p; p += (size_t)M_*3*D_*2;
  unsigned short* Xb1  = qkv;                                          // alias: ln1 out (disjoint live range)
  unsigned short* ctxb = (unsigned short*)p; p += (size_t)M_*D_*2;
  unsigned short* ipwB = (unsigned short*)p; p += (size_t)L_*3*D_*D_*2;
  unsigned short* owB  = (unsigned short*)p; p += (size_t)L_*D_*D_*2;
  unsigned short* w1B  = (unsigned short*)p; p += (size_t)L_*HID_*D_*2;
  unsigned short* w2B  = (unsigned short*)p; p += (size_t)L_*D_*HID_*2;
  unsigned short* XYb  = (unsigned short*)p; p += (size_t)M_*128*2;
  unsigned short* Wemb = (unsigned short*)p; p += (size_t)D_*128*2;
  float* zbias         = (float*)p;          p += 2048*4;
  float* qkvbias       = (float*)p;          p += L_*1536*4;

  // compact layer-6 buffers (alias XYb region, idle post-embed)
  unsigned short* ctxq  = ctxb;                                   // [MQ_,512]
  unsigned short* Ybq   = Yb;                                     // [MQ_,512]
  unsigned short* hidq  = hid;                                    // [MQ_,2048]
  unsigned short* Xqb2  = XYb;                                    // gathered residual
  unsigned short* Xqb1  = XYb + (size_t)MQ_*D_;                   // ln1 out

  (void)hipMemsetAsync(zbias, 0, 2048*4, stream);

  // convert weights to bf16 (Q rows of in_proj pre-scaled by 0.125*log2e)
  f2bq_kernel<<<512, 256, 0, stream>>>(in_proj_w, ipwB, L_*3*D_*D_/4);
  sbias_kernel<<<36, 256, 0, stream>>>(in_proj_b, qkvbias);
  f2b_kernel<<<512, 256, 0, stream>>>(out_w,     owB,  L_*D_*D_/4);
  f2b_kernel<<<512, 256, 0, stream>>>(lin1_w,    w1B,  L_*HID_*D_/4);
  f2b_kernel<<<512, 256, 0, stream>>>(lin2_w,    w2B,  L_*D_*HID_/4);
  wemb_kernel<<<256, 256, 0, stream>>>(W_val, b_val, q_emb, Wemb);
  packxy_kernel<<<1024, 256, 0, stream>>>(x_c, y_c, x_q, XYb);

  // embedding as GEMM (bf16 out -> Xb2), K=128 -> BK=32 kernel
  bgemm_kernel<0,1><<<dim3(4, 144), 256, 0, stream>>>(
      XYb, Wemb, zbias, nullptr, Xb2, D_, 128);

  for (int l = 0; l < L_ - 1; l++) {
    // QKV projection (bf16 out, scaled Q)  (BK=64)
    bgemm128k64_kernel<0><<<dim3(12, 144), 256, 0, stream>>>(
        Xb2, ipwB + (size_t)l*3*D_*D_, qkvbias + (size_t)l*3*D_,
        qkv, 3*D_, D_);
    // attention (full: 18 q-tiles per (b,h))
    mattn_kernel<<<B_*H_*18, 256, 0, stream>>>(qkv, ctxb, 18, 0, S_);
    // out-proj + bf16 residual(Xb2) -> Yb bf16  (BK=64)
    bgemm64_kernel<<<dim3(8, 144), 256, 0, stream>>>(
        ctxb, owB + (size_t)l*D_*D_, out_b + (size_t)l*D_, Xb2, Yb, D_, D_);
    ln_kernel<<<M_, 256, 0, stream>>>(Yb, ln1_g + (size_t)l*D_, ln1_b + (size_t)l*D_, Xb1);
    // FFN1 (relu, bf16 out)  (BK=64)
    bgemm128k64_kernel<1><<<dim3(16, 144), 256, 0, stream>>>(
        Xb1, w1B + (size_t)l*HID_*D_, lin1_b + (size_t)l*HID_,
        hid, HID_, D_);
    // FFN2 + bf16 residual(Xb1) -> Yb  (BK=64)
    bgemm64_kernel<<<dim3(8, 144), 256, 0, stream>>>(
        hid, w2B + (size_t)l*D_*HID_, lin2_b + (size_t)l*D_, Xb1, Yb, D_, HID_);
    ln_kernel<<<M_, 256, 0, stream>>>(Yb, ln2_g + (size_t)l*D_, ln2_b + (size_t)l*D_, Xb2);
  }

  // ---------- layer 6 (l = L_-1): only query rows reach the head ----------
  {
    const int l = L_ - 1;
    bgemm128k64_kernel<0><<<dim3(12, 144), 256, 0, stream>>>(
        Xb2, ipwB + (size_t)l*3*D_*D_, qkvbias + (size_t)l*3*D_,
        qkv, 3*D_, D_);
    // attention only for the 2 query q-tiles per (b,h); compact output [MQ_,512]
    mattn_kernel<<<B_*H_*2, 256, 0, stream>>>(qkv, ctxq, 2, C_, Q_);
    // gather query rows of Xb2 -> Xqb2 (bf16)
    gatherq_kernel<<<MQ_, 256, 0, stream>>>(Xb2, Xqb2);
    // out-proj + residual(Xqb2) -> Ybq (M = 2048)
    bgemm64_kernel<<<dim3(8, 16), 256, 0, stream>>>(
        ctxq, owB + (size_t)l*D_*D_, out_b + (size_t)l*D_, Xqb2, Ybq, D_, D_);
    ln_kernel<<<MQ_, 256, 0, stream>>>(Ybq, ln1_g + (size_t)l*D_, ln1_b + (size_t)l*D_, Xqb1);
    // FFN1 (relu) compact  (BK=64)
    bgemm128k64_kernel<1><<<dim3(16, 16), 256, 0, stream>>>(
        Xqb1, w1B + (size_t)l*HID_*D_, lin1_b + (size_t)l*HID_,
        hidq, HID_, D_);
    // FFN2 + residual(Xqb1) -> Ybq
    bgemm64_kernel<<<dim3(8, 16), 256, 0, stream>>>(
        hidq, w2B + (size_t)l*D_*HID_, lin2_b + (size_t)l*D_, Xqb1, Ybq, D_, HID_);
    // final LN2 -> reuse Xqb2 slot (dead after out-proj)
    ln_kernel<<<MQ_, 256, 0, stream>>>(Ybq, ln2_g + (size_t)l*D_, ln2_b + (size_t)l*D_, Xqb2);
  }

  head_kernel<<<MQ_, 64, 0, stream>>>(Xqb2, W_head, b_head, out);
}